// Round 5
// baseline (3172.890 us; speedup 1.0000x reference)
//
#include <hip/hip_runtime.h>
#include <math.h>

#define DIN 128
#define HID 64

typedef _Float16 h2 __attribute__((ext_vector_type(2)));

__device__ inline float wred_sum(float v) {
#pragma unroll
  for (int d = 1; d < 64; d <<= 1) v += __shfl_xor(v, d, 64);
  return v;
}
__device__ inline float wred_max(float v) {
#pragma unroll
  for (int d = 1; d < 64; d <<= 1) v = fmaxf(v, __shfl_xor(v, d, 64));
  return v;
}
__device__ inline unsigned short f2h(float f) {
  return __builtin_bit_cast(unsigned short, (_Float16)f);
}
__device__ inline h2 bch2(unsigned int u) { return __builtin_bit_cast(h2, u); }
__device__ inline unsigned int h2u(h2 x) { return __builtin_bit_cast(unsigned int, x); }
__device__ inline h2 h2shfl_xor(h2 x, int d) {
  int xi = __builtin_bit_cast(int, x);
  xi = __shfl_xor(xi, d, 64);
  return __builtin_bit_cast(h2, xi);
}

// ---------------- CSR build ----------------
__global__ void k_hist(const int* __restrict__ dst, int* __restrict__ cnt, int E) {
  int e = blockIdx.x * 256 + threadIdx.x;
  if (e < E) atomicAdd(&cnt[dst[e]], 1);
}

__global__ __launch_bounds__(1024) void k_scan(const int* __restrict__ cnt,
                                               int* __restrict__ row,
                                               int* __restrict__ cur, int n) {
  __shared__ int part[1024];
  int t = threadIdx.x;
  int chunk = (n + 1023) >> 10;
  int beg = t * chunk;
  int end = min(beg + chunk, n);
  int s = 0;
  for (int i = beg; i < end; ++i) s += cnt[i];
  part[t] = s;
  __syncthreads();
  for (int d = 1; d < 1024; d <<= 1) {
    int v = (t >= d) ? part[t - d] : 0;
    __syncthreads();
    part[t] += v;
    __syncthreads();
  }
  int off = part[t] - s;  // exclusive
  for (int i = beg; i < end; ++i) {
    int c = cnt[i];
    row[i] = off;
    cur[i] = off;
    off += c;
  }
  if (t == 1023) row[n] = part[1023];
}

__global__ void k_scatter(const int* __restrict__ src, const int* __restrict__ dst,
                          int* __restrict__ cur, int* __restrict__ srcs, int E) {
  int e = blockIdx.x * 256 + threadIdx.x;
  if (e < E) {
    int d = dst[e];
    int pos = atomicAdd(&cur[d], 1);
    srcs[pos] = src[e];
  }
}

// ---------------- embedding: h = x @ emb_w + emb_b (32 nodes/block) ----------------
__global__ __launch_bounds__(256) void k_emb(const float* __restrict__ x,
                                             const float* __restrict__ w,
                                             const float* __restrict__ b,
                                             float* __restrict__ h, int n) {
  __shared__ float xs[32][DIN];
  int tid = threadIdx.x;
  int nb = blockIdx.x * 32;
  for (int t = tid; t < 32 * DIN; t += 256) {
    int ni = t >> 7, k = t & 127;
    int gn = nb + ni;
    xs[ni][k] = (gn < n) ? x[(size_t)gn * DIN + k] : 0.f;
  }
  __syncthreads();
  int col = tid & 63, grp = tid >> 6;  // 4 groups x 8 nodes
  float acc[8];
#pragma unroll
  for (int u = 0; u < 8; ++u) acc[u] = b[col];
  for (int k = 0; k < DIN; k += 4) {
    float w0 = w[k * 64 + col], w1 = w[(k + 1) * 64 + col];
    float w2 = w[(k + 2) * 64 + col], w3 = w[(k + 3) * 64 + col];
#pragma unroll
    for (int u = 0; u < 8; ++u) {
      float4 xv = *(const float4*)&xs[grp * 8 + u][k];
      acc[u] += xv.x * w0 + xv.y * w1 + xv.z * w2 + xv.w * w3;
    }
  }
#pragma unroll
  for (int u = 0; u < 8; ++u) {
    int gn = nb + grp * 8 + u;
    if (gn < n) h[(size_t)gn * 64 + col] = acc[u];
  }
}

// ---------------- QKV (32 nodes/block): Qh[N,128] (pre-scaled), KVh[N,256]=K|V, fp16 ----
__global__ __launch_bounds__(256) void k_qkv(const float* __restrict__ h,
                                             const float* __restrict__ Wq,
                                             const float* __restrict__ Wk,
                                             const float* __restrict__ Wv,
                                             unsigned short* __restrict__ Qh,
                                             unsigned short* __restrict__ KVh, int n) {
  __shared__ float hs[32][64];
  int tid = threadIdx.x;
  int nb = blockIdx.x * 32;
  for (int t = tid; t < 32 * 64; t += 256) {
    int ni = t >> 6, c = t & 63;
    int gn = nb + ni;
    hs[ni][c] = (gn < n) ? h[(size_t)gn * 64 + c] : 0.f;
  }
  __syncthreads();
  int j = tid & 127, grp = tid >> 7;  // 2 groups x 16 nodes
  float aq[16], ak[16], av[16];
#pragma unroll
  for (int u = 0; u < 16; ++u) aq[u] = ak[u] = av[u] = 0.f;
  for (int c = 0; c < 64; c += 4) {
    float wq0 = Wq[c * 128 + j], wq1 = Wq[(c + 1) * 128 + j];
    float wq2 = Wq[(c + 2) * 128 + j], wq3 = Wq[(c + 3) * 128 + j];
    float wk0 = Wk[c * 128 + j], wk1 = Wk[(c + 1) * 128 + j];
    float wk2 = Wk[(c + 2) * 128 + j], wk3 = Wk[(c + 3) * 128 + j];
    float wv0 = Wv[c * 128 + j], wv1 = Wv[(c + 1) * 128 + j];
    float wv2 = Wv[(c + 2) * 128 + j], wv3 = Wv[(c + 3) * 128 + j];
#pragma unroll
    for (int u = 0; u < 16; ++u) {
      float4 hv = *(const float4*)&hs[grp * 16 + u][c];
      aq[u] += hv.x * wq0 + hv.y * wq1 + hv.z * wq2 + hv.w * wq3;
      ak[u] += hv.x * wk0 + hv.y * wk1 + hv.z * wk2 + hv.w * wk3;
      av[u] += hv.x * wv0 + hv.y * wv1 + hv.z * wv2 + hv.w * wv3;
    }
  }
#pragma unroll
  for (int u = 0; u < 16; ++u) {
    int gn = nb + grp * 16 + u;
    if (gn < n) {
      Qh[(size_t)gn * 128 + j] = f2h(aq[u] * 0.125f);
      KVh[(size_t)gn * 256 + j] = f2h(ak[u]);
      KVh[(size_t)gn * 256 + 128 + j] = f2h(av[u]);
    }
  }
}

// ---------------- attention gather+softmax: aggrh[N,128] fp16 normalized ----------------
// One node/wave; 4 edges/iter (16 lanes each: octet 0 = head0's 64 cols, octet 1 = head1).
// 4-slot K/V pipeline + src indices prefetched 8 sub-iters ahead.
__global__ __launch_bounds__(256) void k_attn(
    const unsigned short* __restrict__ Qh, const unsigned short* __restrict__ KVh,
    const int* __restrict__ row, const int* __restrict__ srcs,
    unsigned short* __restrict__ aggrh, int n) {
  int lane = threadIdx.x & 63;
  int w = threadIdx.x >> 6;
  int node = blockIdx.x * 4 + w;
  if (node >= n) return;  // no barriers in this kernel
  int sl = lane & 15, gi = lane >> 4;

  uint4 qr = *(const uint4*)(Qh + (size_t)node * 128 + sl * 8);
  h2 q0 = bch2(qr.x), q1 = bch2(qr.y), q2 = bch2(qr.z), q3 = bch2(qr.w);

  int rs = row[node], re = row[node + 1];
  int deg = re - rs;
  float den = 0.f;
  h2 acc0 = {0, 0}, acc1 = {0, 0}, acc2 = {0, 0}, acc3 = {0, 0};

  if (deg > 0) {
    int iters = (deg + 3) >> 2;
    uint4 Kb[4], Vb[4];
    int sxb[4];
#pragma unroll
    for (int s = 0; s < 4; ++s) {
      if (s < iters) {
        int ei = rs + s * 4 + gi;
        int sx = (ei < re) ? srcs[ei] : srcs[rs];
        const unsigned short* kv = KVh + (size_t)sx * 256 + sl * 8;
        Kb[s] = *(const uint4*)kv;
        Vb[s] = *(const uint4*)(kv + 128);
      }
      int ei2 = rs + (s + 4) * 4 + gi;
      sxb[s] = (ei2 < re) ? srcs[ei2] : srcs[rs];
    }
    for (int it = 0; it < iters; it += 4) {
#pragma unroll
      for (int s = 0; s < 4; ++s) {
        int cit = it + s;
        if (cit < iters) {  // wave-uniform
          uint4 Kc = Kb[s], Vc = Vb[s];
          if (cit + 4 < iters) {  // refill slot from prefetched index
            const unsigned short* kv = KVh + (size_t)sxb[s] * 256 + sl * 8;
            Kb[s] = *(const uint4*)kv;
            Vb[s] = *(const uint4*)(kv + 128);
          }
          {  // prefetch src index 8 sub-iters ahead
            int ei3 = rs + (cit + 8) * 4 + gi;
            sxb[s] = (ei3 < re) ? srcs[ei3] : srcs[rs];
          }
          float sc = __builtin_amdgcn_fdot2(bch2(Kc.x), q0, 0.f, false);
          sc = __builtin_amdgcn_fdot2(bch2(Kc.y), q1, sc, false);
          sc = __builtin_amdgcn_fdot2(bch2(Kc.z), q2, sc, false);
          sc = __builtin_amdgcn_fdot2(bch2(Kc.w), q3, sc, false);
          sc += __shfl_xor(sc, 1, 64);
          sc += __shfl_xor(sc, 2, 64);
          sc += __shfl_xor(sc, 4, 64);  // octet-sum: head (sl>>3) score of edge gi
          bool ev = (rs + cit * 4 + gi) < re;
          float wgt = ev ? __expf(sc) : 0.f;
          den += wgt;
          _Float16 wh = (_Float16)wgt;
          h2 W = {wh, wh};
          acc0 += W * bch2(Vc.x);
          acc1 += W * bch2(Vc.y);
          acc2 += W * bch2(Vc.z);
          acc3 += W * bch2(Vc.w);
        }
      }
    }
  }
  // combine 4 edge groups
#pragma unroll
  for (int d = 16; d < 64; d <<= 1) {
    den += __shfl_xor(den, d, 64);
    acc0 += h2shfl_xor(acc0, d);
    acc1 += h2shfl_xor(acc1, d);
    acc2 += h2shfl_xor(acc2, d);
    acc3 += h2shfl_xor(acc3, d);
  }
  float inv = fminf(1.f / (den + 1e-16f), 60000.f);  // clamp so fp16 stays finite
  if (lane < 16) {
    _Float16 ih = (_Float16)inv;
    h2 I = {ih, ih};
    uint4 o;
    o.x = h2u(acc0 * I);
    o.y = h2u(acc1 * I);
    o.z = h2u(acc2 * I);
    o.w = h2u(acc3 * I);
    *(uint4*)(aggrh + (size_t)node * 128 + sl * 8) = o;
  }
}

// ---------------- post: Wout -> +res -> LN -> FFN (16 nodes/block, 4/wave) ----------------
__global__ __launch_bounds__(256, 4) void k_post(
    const unsigned short* __restrict__ aggrh, float* __restrict__ h,
    const float* __restrict__ Wout, const float* __restrict__ bout,
    const float* __restrict__ lng, const float* __restrict__ lnb,
    const float* __restrict__ W1, const float* __restrict__ b1,
    const float* __restrict__ W2, const float* __restrict__ b2, int n) {
  __shared__ float s_a[16][128];
  __shared__ float s_h[16][64];
  __shared__ float s_t[16][64];
  int tid = threadIdx.x;
  int nb = blockIdx.x * 16;
  for (int t = tid; t < 16 * 64; t += 256) {  // 1024 uints = 2048 halfs
    int ni = t >> 6;
    int p2 = (t & 63) * 2;
    int gn = nb + ni;
    unsigned int u = (gn < n) ? *(const unsigned int*)(aggrh + (size_t)gn * 128 + p2) : 0u;
    h2 v = bch2(u);
    s_a[ni][p2] = (float)v[0];
    s_a[ni][p2 + 1] = (float)v[1];
  }
  __syncthreads();
  int lane = tid & 63, wv = tid >> 6;  // wave handles 4 nodes
  float o[4];
#pragma unroll
  for (int u = 0; u < 4; ++u) o[u] = bout[lane];
  for (int j = 0; j < 128; j += 4) {
    float w0 = Wout[j * 64 + lane], w1 = Wout[(j + 1) * 64 + lane];
    float w2 = Wout[(j + 2) * 64 + lane], w3 = Wout[(j + 3) * 64 + lane];
#pragma unroll
    for (int u = 0; u < 4; ++u) {
      float4 a = *(const float4*)&s_a[wv * 4 + u][j];
      o[u] += a.x * w0 + a.y * w1 + a.z * w2 + a.w * w3;
    }
  }
  float hl[4];
#pragma unroll
  for (int u = 0; u < 4; ++u) {
    int gn = nb + wv * 4 + u;
    float xv = o[u] + ((gn < n) ? h[(size_t)gn * 64 + lane] : 0.f);
    float mu = wred_sum(xv) * (1.f / 64.f);
    float xc = xv - mu;
    float var = wred_sum(xc * xc) * (1.f / 64.f);
    hl[u] = xc * rsqrtf(var + 1e-5f) * lng[lane] + lnb[lane];
    s_h[wv * 4 + u][lane] = hl[u];
  }
  __syncthreads();
  float t1[4];
#pragma unroll
  for (int u = 0; u < 4; ++u) t1[u] = b1[lane];
  for (int j = 0; j < 64; j += 4) {
    float w0 = W1[j * 64 + lane], w1 = W1[(j + 1) * 64 + lane];
    float w2 = W1[(j + 2) * 64 + lane], w3 = W1[(j + 3) * 64 + lane];
#pragma unroll
    for (int u = 0; u < 4; ++u) {
      float4 a = *(const float4*)&s_h[wv * 4 + u][j];
      t1[u] += a.x * w0 + a.y * w1 + a.z * w2 + a.w * w3;
    }
  }
#pragma unroll
  for (int u = 0; u < 4; ++u) s_t[wv * 4 + u][lane] = fmaxf(t1[u], 0.f);
  __syncthreads();
  float o2[4];
#pragma unroll
  for (int u = 0; u < 4; ++u) o2[u] = b2[lane];
  for (int j = 0; j < 64; j += 4) {
    float w0 = W2[j * 64 + lane], w1 = W2[(j + 1) * 64 + lane];
    float w2 = W2[(j + 2) * 64 + lane], w3 = W2[(j + 3) * 64 + lane];
#pragma unroll
    for (int u = 0; u < 4; ++u) {
      float4 a = *(const float4*)&s_t[wv * 4 + u][j];
      o2[u] += a.x * w0 + a.y * w1 + a.z * w2 + a.w * w3;
    }
  }
#pragma unroll
  for (int u = 0; u < 4; ++u) {
    int gn = nb + wv * 4 + u;
    if (gn < n) h[(size_t)gn * 64 + lane] = hl[u] + o2[u];
  }
}

// ---------------- output: log_softmax(h @ out_w + out_b) (16 nodes/block) ----------------
__global__ __launch_bounds__(256) void k_out(const float* __restrict__ h,
                                             const float* __restrict__ w,
                                             const float* __restrict__ b,
                                             float* __restrict__ out, int n) {
  __shared__ float s_h[16][64];
  int tid = threadIdx.x;
  int nb = blockIdx.x * 16;
  for (int t = tid; t < 16 * 64; t += 256) {
    int ni = t >> 6;
    int gn = nb + ni;
    s_h[ni][t & 63] = (gn < n) ? h[(size_t)gn * 64 + (t & 63)] : 0.f;
  }
  __syncthreads();
  int lane = tid & 63, wv = tid >> 6;
  for (int u = 0; u < 4; ++u) {
    int li = wv * 4 + u;
    int node = nb + li;
    float lv = -3.0e38f;
    if (lane < 40) {
      lv = b[lane];
#pragma unroll 8
      for (int j = 0; j < 64; ++j) lv += s_h[li][j] * w[j * 40 + lane];
    }
    float m = wred_max(lv);
    float ex = (lane < 40) ? __expf(lv - m) : 0.f;
    float s = wred_sum(ex);
    if (node < n && lane < 40) out[(size_t)node * 40 + lane] = lv - m - logf(s);
  }
}

extern "C" void kernel_launch(void* const* d_in, const int* in_sizes, int n_in,
                              void* d_out, int out_size, void* d_ws, size_t ws_size,
                              hipStream_t stream) {
  const float* x     = (const float*)d_in[0];
  const int*   ei    = (const int*)d_in[1];
  const float* emb_w = (const float*)d_in[2];
  const float* emb_b = (const float*)d_in[3];
  const float* Wq    = (const float*)d_in[4];   // [2,64,128]
  const float* Wk    = (const float*)d_in[5];
  const float* Wv    = (const float*)d_in[6];
  const float* Wout  = (const float*)d_in[7];   // [2,128,64]
  const float* bout  = (const float*)d_in[8];
  const float* ln_g  = (const float*)d_in[9];
  const float* ln_b  = (const float*)d_in[10];
  const float* W1    = (const float*)d_in[11];  // [2,64,64]
  const float* b1    = (const float*)d_in[12];
  const float* W2    = (const float*)d_in[13];
  const float* b2    = (const float*)d_in[14];
  const float* out_w = (const float*)d_in[15];  // [64,40]
  const float* out_b = (const float*)d_in[16];
  float* out = (float*)d_out;

  const int n = in_sizes[0] / DIN;  // 50000
  const int E = in_sizes[1] / 2;    // 800000

  char* ws = (char*)d_ws;
  size_t off = 0;
  auto alloc = [&](size_t bytes) {
    void* p = ws + off;
    off = (off + bytes + 255) & ~(size_t)255;
    return p;
  };
  float* h              = (float*)alloc((size_t)n * 64 * 4);
  unsigned short* Qh    = (unsigned short*)alloc((size_t)n * 128 * 2);
  unsigned short* KVh   = (unsigned short*)alloc((size_t)n * 256 * 2);
  unsigned short* aggrh = (unsigned short*)alloc((size_t)n * 128 * 2);
  int* cnt              = (int*)alloc((size_t)n * 4);
  int* rowp             = (int*)alloc((size_t)(n + 1) * 4);
  int* cur              = (int*)alloc((size_t)n * 4);
  int* srcs             = (int*)alloc((size_t)E * 4);

  const int* src = ei;
  const int* dst = ei + E;

  hipMemsetAsync(cnt, 0, (size_t)n * 4, stream);
  k_hist<<<(E + 255) / 256, 256, 0, stream>>>(dst, cnt, E);
  k_scan<<<1, 1024, 0, stream>>>(cnt, rowp, cur, n);
  k_scatter<<<(E + 255) / 256, 256, 0, stream>>>(src, dst, cur, srcs, E);

  k_emb<<<(n + 31) / 32, 256, 0, stream>>>(x, emb_w, emb_b, h, n);

  for (int l = 0; l < 2; ++l) {
    k_qkv<<<(n + 31) / 32, 256, 0, stream>>>(h, Wq + (size_t)l * 64 * 128,
                                             Wk + (size_t)l * 64 * 128,
                                             Wv + (size_t)l * 64 * 128, Qh, KVh, n);
    k_attn<<<(n + 3) / 4, 256, 0, stream>>>(Qh, KVh, rowp, srcs, aggrh, n);
    k_post<<<(n + 15) / 16, 256, 0, stream>>>(
        aggrh, h, Wout + (size_t)l * 128 * 64, bout + (size_t)l * 64,
        ln_g + (size_t)l * 64, ln_b + (size_t)l * 64, W1 + (size_t)l * 64 * 64,
        b1 + (size_t)l * 64, W2 + (size_t)l * 64 * 64, b2 + (size_t)l * 64, n);
  }

  k_out<<<(n + 15) / 16, 256, 0, stream>>>(h, out_w, out_b, out, n);
}

// Round 6
// 775.989 us; speedup vs baseline: 4.0888x; 4.0888x over previous
//
#include <hip/hip_runtime.h>
#include <math.h>

#define DIN 128
#define HID 64

typedef _Float16 h2 __attribute__((ext_vector_type(2)));

__device__ inline float wred_sum(float v) {
#pragma unroll
  for (int d = 1; d < 64; d <<= 1) v += __shfl_xor(v, d, 64);
  return v;
}
__device__ inline float wred_max(float v) {
#pragma unroll
  for (int d = 1; d < 64; d <<= 1) v = fmaxf(v, __shfl_xor(v, d, 64));
  return v;
}
__device__ inline unsigned short f2h(float f) {
  return __builtin_bit_cast(unsigned short, (_Float16)f);
}
__device__ inline h2 bch2(unsigned int u) { return __builtin_bit_cast(h2, u); }
__device__ inline unsigned int h2u(h2 x) { return __builtin_bit_cast(unsigned int, x); }
__device__ inline h2 h2shfl_xor(h2 x, int d) {
  int xi = __builtin_bit_cast(int, x);
  xi = __shfl_xor(xi, d, 64);
  return __builtin_bit_cast(h2, xi);
}

// ---------------- CSR build ----------------
__global__ void k_hist(const int* __restrict__ dst, int* __restrict__ cnt, int E) {
  int e = blockIdx.x * 256 + threadIdx.x;
  if (e < E) atomicAdd(&cnt[dst[e]], 1);
}

__global__ __launch_bounds__(1024) void k_scan(const int* __restrict__ cnt,
                                               int* __restrict__ row,
                                               int* __restrict__ cur, int n) {
  __shared__ int part[1024];
  int t = threadIdx.x;
  int chunk = (n + 1023) >> 10;
  int beg = t * chunk;
  int end = min(beg + chunk, n);
  int s = 0;
  for (int i = beg; i < end; ++i) s += cnt[i];
  part[t] = s;
  __syncthreads();
  for (int d = 1; d < 1024; d <<= 1) {
    int v = (t >= d) ? part[t - d] : 0;
    __syncthreads();
    part[t] += v;
    __syncthreads();
  }
  int off = part[t] - s;  // exclusive
  for (int i = beg; i < end; ++i) {
    int c = cnt[i];
    row[i] = off;
    cur[i] = off;
    off += c;
  }
  if (t == 1023) row[n] = part[1023];
}

__global__ void k_scatter(const int* __restrict__ src, const int* __restrict__ dst,
                          int* __restrict__ cur, int* __restrict__ srcs, int E) {
  int e = blockIdx.x * 256 + threadIdx.x;
  if (e < E) {
    int d = dst[e];
    int pos = atomicAdd(&cur[d], 1);
    srcs[pos] = src[e];
  }
}

// ---------------- embedding: h = x @ emb_w + emb_b (32 nodes/block) ----------------
__global__ __launch_bounds__(256) void k_emb(const float* __restrict__ x,
                                             const float* __restrict__ w,
                                             const float* __restrict__ b,
                                             float* __restrict__ h, int n) {
  __shared__ float xs[32][DIN];
  int tid = threadIdx.x;
  int nb = blockIdx.x * 32;
  for (int t = tid; t < 32 * DIN; t += 256) {
    int ni = t >> 7, k = t & 127;
    int gn = nb + ni;
    xs[ni][k] = (gn < n) ? x[(size_t)gn * DIN + k] : 0.f;
  }
  __syncthreads();
  int col = tid & 63, grp = tid >> 6;  // 4 groups x 8 nodes
  float acc[8];
#pragma unroll
  for (int u = 0; u < 8; ++u) acc[u] = b[col];
  for (int k = 0; k < DIN; k += 4) {
    float w0 = w[k * 64 + col], w1 = w[(k + 1) * 64 + col];
    float w2 = w[(k + 2) * 64 + col], w3 = w[(k + 3) * 64 + col];
#pragma unroll
    for (int u = 0; u < 8; ++u) {
      float4 xv = *(const float4*)&xs[grp * 8 + u][k];
      acc[u] += xv.x * w0 + xv.y * w1 + xv.z * w2 + xv.w * w3;
    }
  }
#pragma unroll
  for (int u = 0; u < 8; ++u) {
    int gn = nb + grp * 8 + u;
    if (gn < n) h[(size_t)gn * 64 + col] = acc[u];
  }
}

// ---------------- QKV (32 nodes/block): Qh[N,128] (pre-scaled), KVh[N,256]=K|V, fp16 ----
__global__ __launch_bounds__(256) void k_qkv(const float* __restrict__ h,
                                             const float* __restrict__ Wq,
                                             const float* __restrict__ Wk,
                                             const float* __restrict__ Wv,
                                             unsigned short* __restrict__ Qh,
                                             unsigned short* __restrict__ KVh, int n) {
  __shared__ float hs[32][64];
  int tid = threadIdx.x;
  int nb = blockIdx.x * 32;
  for (int t = tid; t < 32 * 64; t += 256) {
    int ni = t >> 6, c = t & 63;
    int gn = nb + ni;
    hs[ni][c] = (gn < n) ? h[(size_t)gn * 64 + c] : 0.f;
  }
  __syncthreads();
  int j = tid & 127, grp = tid >> 7;  // 2 groups x 16 nodes
  float aq[16], ak[16], av[16];
#pragma unroll
  for (int u = 0; u < 16; ++u) aq[u] = ak[u] = av[u] = 0.f;
  for (int c = 0; c < 64; c += 4) {
    float wq0 = Wq[c * 128 + j], wq1 = Wq[(c + 1) * 128 + j];
    float wq2 = Wq[(c + 2) * 128 + j], wq3 = Wq[(c + 3) * 128 + j];
    float wk0 = Wk[c * 128 + j], wk1 = Wk[(c + 1) * 128 + j];
    float wk2 = Wk[(c + 2) * 128 + j], wk3 = Wk[(c + 3) * 128 + j];
    float wv0 = Wv[c * 128 + j], wv1 = Wv[(c + 1) * 128 + j];
    float wv2 = Wv[(c + 2) * 128 + j], wv3 = Wv[(c + 3) * 128 + j];
#pragma unroll
    for (int u = 0; u < 16; ++u) {
      float4 hv = *(const float4*)&hs[grp * 16 + u][c];
      aq[u] += hv.x * wq0 + hv.y * wq1 + hv.z * wq2 + hv.w * wq3;
      ak[u] += hv.x * wk0 + hv.y * wk1 + hv.z * wk2 + hv.w * wk3;
      av[u] += hv.x * wv0 + hv.y * wv1 + hv.z * wv2 + hv.w * wv3;
    }
  }
#pragma unroll
  for (int u = 0; u < 16; ++u) {
    int gn = nb + grp * 16 + u;
    if (gn < n) {
      Qh[(size_t)gn * 128 + j] = f2h(aq[u] * 0.125f);
      KVh[(size_t)gn * 256 + j] = f2h(ak[u]);
      KVh[(size_t)gn * 256 + 128 + j] = f2h(av[u]);
    }
  }
}

// ---------------- attention gather+softmax: aggrh[N,128] fp16 normalized ----------------
// One node/wave; 4 edges/iter (16 lanes each: octet 0 = head0's 64 cols, octet 1 = head1).
// 4-slot K/V pipeline + src indices prefetched 8 sub-iters ahead.
__global__ __launch_bounds__(256) void k_attn(
    const unsigned short* __restrict__ Qh, const unsigned short* __restrict__ KVh,
    const int* __restrict__ row, const int* __restrict__ srcs,
    unsigned short* __restrict__ aggrh, int n) {
  int lane = threadIdx.x & 63;
  int w = threadIdx.x >> 6;
  int node = blockIdx.x * 4 + w;
  if (node >= n) return;  // no barriers in this kernel
  int sl = lane & 15, gi = lane >> 4;

  uint4 qr = *(const uint4*)(Qh + (size_t)node * 128 + sl * 8);
  h2 q0 = bch2(qr.x), q1 = bch2(qr.y), q2 = bch2(qr.z), q3 = bch2(qr.w);

  int rs = row[node], re = row[node + 1];
  int deg = re - rs;
  float den = 0.f;
  h2 acc0 = {0, 0}, acc1 = {0, 0}, acc2 = {0, 0}, acc3 = {0, 0};

  if (deg > 0) {
    int iters = (deg + 3) >> 2;
    uint4 Kb[4], Vb[4];
    int sxb[4];
#pragma unroll
    for (int s = 0; s < 4; ++s) {
      if (s < iters) {
        int ei = rs + s * 4 + gi;
        int sx = (ei < re) ? srcs[ei] : srcs[rs];
        const unsigned short* kv = KVh + (size_t)sx * 256 + sl * 8;
        Kb[s] = *(const uint4*)kv;
        Vb[s] = *(const uint4*)(kv + 128);
      }
      int ei2 = rs + (s + 4) * 4 + gi;
      sxb[s] = (ei2 < re) ? srcs[ei2] : srcs[rs];
    }
    for (int it = 0; it < iters; it += 4) {
#pragma unroll
      for (int s = 0; s < 4; ++s) {
        int cit = it + s;
        if (cit < iters) {  // wave-uniform
          uint4 Kc = Kb[s], Vc = Vb[s];
          if (cit + 4 < iters) {  // refill slot from prefetched index
            const unsigned short* kv = KVh + (size_t)sxb[s] * 256 + sl * 8;
            Kb[s] = *(const uint4*)kv;
            Vb[s] = *(const uint4*)(kv + 128);
          }
          {  // prefetch src index 8 sub-iters ahead
            int ei3 = rs + (cit + 8) * 4 + gi;
            sxb[s] = (ei3 < re) ? srcs[ei3] : srcs[rs];
          }
          float sc = __builtin_amdgcn_fdot2(bch2(Kc.x), q0, 0.f, false);
          sc = __builtin_amdgcn_fdot2(bch2(Kc.y), q1, sc, false);
          sc = __builtin_amdgcn_fdot2(bch2(Kc.z), q2, sc, false);
          sc = __builtin_amdgcn_fdot2(bch2(Kc.w), q3, sc, false);
          sc += __shfl_xor(sc, 1, 64);
          sc += __shfl_xor(sc, 2, 64);
          sc += __shfl_xor(sc, 4, 64);  // octet-sum: head (sl>>3) score of edge gi
          bool ev = (rs + cit * 4 + gi) < re;
          float wgt = ev ? __expf(sc) : 0.f;
          den += wgt;
          _Float16 wh = (_Float16)wgt;
          h2 W = {wh, wh};
          acc0 += W * bch2(Vc.x);
          acc1 += W * bch2(Vc.y);
          acc2 += W * bch2(Vc.z);
          acc3 += W * bch2(Vc.w);
        }
      }
    }
  }
  // combine 4 edge groups
#pragma unroll
  for (int d = 16; d < 64; d <<= 1) {
    den += __shfl_xor(den, d, 64);
    acc0 += h2shfl_xor(acc0, d);
    acc1 += h2shfl_xor(acc1, d);
    acc2 += h2shfl_xor(acc2, d);
    acc3 += h2shfl_xor(acc3, d);
  }
  float inv = fminf(1.f / (den + 1e-16f), 60000.f);  // clamp so fp16 stays finite
  if (lane < 16) {
    _Float16 ih = (_Float16)inv;
    h2 I = {ih, ih};
    uint4 o;
    o.x = h2u(acc0 * I);
    o.y = h2u(acc1 * I);
    o.z = h2u(acc2 * I);
    o.w = h2u(acc3 * I);
    *(uint4*)(aggrh + (size_t)node * 128 + sl * 8) = o;
  }
}

// ---------------- post: Wout -> +res -> LN -> FFN (8 nodes/block, 2/wave) ----------------
// NOTE: no second __launch_bounds__ arg — forcing 4 waves/EU previously capped the
// allocator at 64 VGPR and spilled 3.8 GB to scratch (round 5). Natural allocation
// at 2 nodes/wave stays well under 128 VGPR with zero spill.
__global__ __launch_bounds__(256) void k_post(
    const unsigned short* __restrict__ aggrh, float* __restrict__ h,
    const float* __restrict__ Wout, const float* __restrict__ bout,
    const float* __restrict__ lng, const float* __restrict__ lnb,
    const float* __restrict__ W1, const float* __restrict__ b1,
    const float* __restrict__ W2, const float* __restrict__ b2, int n) {
  __shared__ float s_a[8][128];
  __shared__ float s_h[8][64];
  __shared__ float s_t[8][64];
  int tid = threadIdx.x;
  int nb = blockIdx.x * 8;
  for (int t = tid; t < 8 * 64; t += 256) {  // 512 uints = 1024 halfs
    int ni = t >> 6;
    int p2 = (t & 63) * 2;
    int gn = nb + ni;
    unsigned int u = (gn < n) ? *(const unsigned int*)(aggrh + (size_t)gn * 128 + p2) : 0u;
    h2 v = bch2(u);
    s_a[ni][p2] = (float)v[0];
    s_a[ni][p2 + 1] = (float)v[1];
  }
  __syncthreads();
  int lane = tid & 63, wv = tid >> 6;  // wave handles 2 nodes
  float o0 = bout[lane], o1 = o0;
  for (int j = 0; j < 128; j += 4) {
    float w0 = Wout[j * 64 + lane], w1 = Wout[(j + 1) * 64 + lane];
    float w2 = Wout[(j + 2) * 64 + lane], w3 = Wout[(j + 3) * 64 + lane];
    float4 a0 = *(const float4*)&s_a[wv * 2][j];
    float4 a1 = *(const float4*)&s_a[wv * 2 + 1][j];
    o0 += a0.x * w0 + a0.y * w1 + a0.z * w2 + a0.w * w3;
    o1 += a1.x * w0 + a1.y * w1 + a1.z * w2 + a1.w * w3;
  }
  float hl0, hl1;
  {
    int gn = nb + wv * 2;
    float xv = o0 + ((gn < n) ? h[(size_t)gn * 64 + lane] : 0.f);
    float mu = wred_sum(xv) * (1.f / 64.f);
    float xc = xv - mu;
    float var = wred_sum(xc * xc) * (1.f / 64.f);
    hl0 = xc * rsqrtf(var + 1e-5f) * lng[lane] + lnb[lane];
    s_h[wv * 2][lane] = hl0;
  }
  {
    int gn = nb + wv * 2 + 1;
    float xv = o1 + ((gn < n) ? h[(size_t)gn * 64 + lane] : 0.f);
    float mu = wred_sum(xv) * (1.f / 64.f);
    float xc = xv - mu;
    float var = wred_sum(xc * xc) * (1.f / 64.f);
    hl1 = xc * rsqrtf(var + 1e-5f) * lng[lane] + lnb[lane];
    s_h[wv * 2 + 1][lane] = hl1;
  }
  __syncthreads();
  float t0 = b1[lane], t1 = t0;
  for (int j = 0; j < 64; j += 4) {
    float w0 = W1[j * 64 + lane], w1 = W1[(j + 1) * 64 + lane];
    float w2 = W1[(j + 2) * 64 + lane], w3 = W1[(j + 3) * 64 + lane];
    float4 a0 = *(const float4*)&s_h[wv * 2][j];
    float4 a1 = *(const float4*)&s_h[wv * 2 + 1][j];
    t0 += a0.x * w0 + a0.y * w1 + a0.z * w2 + a0.w * w3;
    t1 += a1.x * w0 + a1.y * w1 + a1.z * w2 + a1.w * w3;
  }
  s_t[wv * 2][lane] = fmaxf(t0, 0.f);
  s_t[wv * 2 + 1][lane] = fmaxf(t1, 0.f);
  __syncthreads();
  float p0 = b2[lane], p1 = p0;
  for (int j = 0; j < 64; j += 4) {
    float w0 = W2[j * 64 + lane], w1 = W2[(j + 1) * 64 + lane];
    float w2 = W2[(j + 2) * 64 + lane], w3 = W2[(j + 3) * 64 + lane];
    float4 a0 = *(const float4*)&s_t[wv * 2][j];
    float4 a1 = *(const float4*)&s_t[wv * 2 + 1][j];
    p0 += a0.x * w0 + a0.y * w1 + a0.z * w2 + a0.w * w3;
    p1 += a1.x * w0 + a1.y * w1 + a1.z * w2 + a1.w * w3;
  }
  {
    int gn = nb + wv * 2;
    if (gn < n) h[(size_t)gn * 64 + lane] = hl0 + p0;
  }
  {
    int gn = nb + wv * 2 + 1;
    if (gn < n) h[(size_t)gn * 64 + lane] = hl1 + p1;
  }
}

// ---------------- output: log_softmax(h @ out_w + out_b) (16 nodes/block) ----------------
__global__ __launch_bounds__(256) void k_out(const float* __restrict__ h,
                                             const float* __restrict__ w,
                                             const float* __restrict__ b,
                                             float* __restrict__ out, int n) {
  __shared__ float s_h[16][64];
  int tid = threadIdx.x;
  int nb = blockIdx.x * 16;
  for (int t = tid; t < 16 * 64; t += 256) {
    int ni = t >> 6;
    int gn = nb + ni;
    s_h[ni][t & 63] = (gn < n) ? h[(size_t)gn * 64 + (t & 63)] : 0.f;
  }
  __syncthreads();
  int lane = tid & 63, wv = tid >> 6;
  for (int u = 0; u < 4; ++u) {
    int li = wv * 4 + u;
    int node = nb + li;
    float lv = -3.0e38f;
    if (lane < 40) {
      lv = b[lane];
#pragma unroll 8
      for (int j = 0; j < 64; ++j) lv += s_h[li][j] * w[j * 40 + lane];
    }
    float m = wred_max(lv);
    float ex = (lane < 40) ? __expf(lv - m) : 0.f;
    float s = wred_sum(ex);
    if (node < n && lane < 40) out[(size_t)node * 40 + lane] = lv - m - logf(s);
  }
}

extern "C" void kernel_launch(void* const* d_in, const int* in_sizes, int n_in,
                              void* d_out, int out_size, void* d_ws, size_t ws_size,
                              hipStream_t stream) {
  const float* x     = (const float*)d_in[0];
  const int*   ei    = (const int*)d_in[1];
  const float* emb_w = (const float*)d_in[2];
  const float* emb_b = (const float*)d_in[3];
  const float* Wq    = (const float*)d_in[4];   // [2,64,128]
  const float* Wk    = (const float*)d_in[5];
  const float* Wv    = (const float*)d_in[6];
  const float* Wout  = (const float*)d_in[7];   // [2,128,64]
  const float* bout  = (const float*)d_in[8];
  const float* ln_g  = (const float*)d_in[9];
  const float* ln_b  = (const float*)d_in[10];
  const float* W1    = (const float*)d_in[11];  // [2,64,64]
  const float* b1    = (const float*)d_in[12];
  const float* W2    = (const float*)d_in[13];
  const float* b2    = (const float*)d_in[14];
  const float* out_w = (const float*)d_in[15];  // [64,40]
  const float* out_b = (const float*)d_in[16];
  float* out = (float*)d_out;

  const int n = in_sizes[0] / DIN;  // 50000
  const int E = in_sizes[1] / 2;    // 800000

  char* ws = (char*)d_ws;
  size_t off = 0;
  auto alloc = [&](size_t bytes) {
    void* p = ws + off;
    off = (off + bytes + 255) & ~(size_t)255;
    return p;
  };
  float* h              = (float*)alloc((size_t)n * 64 * 4);
  unsigned short* Qh    = (unsigned short*)alloc((size_t)n * 128 * 2);
  unsigned short* KVh   = (unsigned short*)alloc((size_t)n * 256 * 2);
  unsigned short* aggrh = (unsigned short*)alloc((size_t)n * 128 * 2);
  int* cnt              = (int*)alloc((size_t)n * 4);
  int* rowp             = (int*)alloc((size_t)(n + 1) * 4);
  int* cur              = (int*)alloc((size_t)n * 4);
  int* srcs             = (int*)alloc((size_t)E * 4);

  const int* src = ei;
  const int* dst = ei + E;

  hipMemsetAsync(cnt, 0, (size_t)n * 4, stream);
  k_hist<<<(E + 255) / 256, 256, 0, stream>>>(dst, cnt, E);
  k_scan<<<1, 1024, 0, stream>>>(cnt, rowp, cur, n);
  k_scatter<<<(E + 255) / 256, 256, 0, stream>>>(src, dst, cur, srcs, E);

  k_emb<<<(n + 31) / 32, 256, 0, stream>>>(x, emb_w, emb_b, h, n);

  for (int l = 0; l < 2; ++l) {
    k_qkv<<<(n + 31) / 32, 256, 0, stream>>>(h, Wq + (size_t)l * 64 * 128,
                                             Wk + (size_t)l * 64 * 128,
                                             Wv + (size_t)l * 64 * 128, Qh, KVh, n);
    k_attn<<<(n + 3) / 4, 256, 0, stream>>>(Qh, KVh, rowp, srcs, aggrh, n);
    k_post<<<(n + 7) / 8, 256, 0, stream>>>(
        aggrh, h, Wout + (size_t)l * 128 * 64, bout + (size_t)l * 64,
        ln_g + (size_t)l * 64, ln_b + (size_t)l * 64, W1 + (size_t)l * 64 * 64,
        b1 + (size_t)l * 64, W2 + (size_t)l * 64 * 64, b2 + (size_t)l * 64, n);
  }

  k_out<<<(n + 15) / 16, 256, 0, stream>>>(h, out_w, out_b, out, n);
}

// Round 7
// 508.354 us; speedup vs baseline: 6.2415x; 1.5265x over previous
//
#include <hip/hip_runtime.h>
#include <math.h>

#define DIN 128
#define HID 64

typedef _Float16 h2 __attribute__((ext_vector_type(2)));
typedef _Float16 f16x8 __attribute__((ext_vector_type(8)));
typedef float f32x4 __attribute__((ext_vector_type(4)));

__device__ inline float wred_sum(float v) {
#pragma unroll
  for (int d = 1; d < 64; d <<= 1) v += __shfl_xor(v, d, 64);
  return v;
}
__device__ inline float wred_max(float v) {
#pragma unroll
  for (int d = 1; d < 64; d <<= 1) v = fmaxf(v, __shfl_xor(v, d, 64));
  return v;
}
__device__ inline unsigned short f2h(float f) {
  return __builtin_bit_cast(unsigned short, (_Float16)f);
}
__device__ inline h2 bch2(unsigned int u) { return __builtin_bit_cast(h2, u); }
__device__ inline unsigned int h2u(h2 x) { return __builtin_bit_cast(unsigned int, x); }
__device__ inline f16x8 bcf16x8(uint4 u) { return __builtin_bit_cast(f16x8, u); }
__device__ inline h2 h2shfl_xor(h2 x, int d) {
  int xi = __builtin_bit_cast(int, x);
  xi = __shfl_xor(xi, d, 64);
  return __builtin_bit_cast(h2, xi);
}

// ---------------- CSR build ----------------
__global__ void k_hist(const int* __restrict__ dst, int* __restrict__ cnt, int E) {
  int e = blockIdx.x * 256 + threadIdx.x;
  if (e < E) atomicAdd(&cnt[dst[e]], 1);
}

__global__ __launch_bounds__(1024) void k_scan(const int* __restrict__ cnt,
                                               int* __restrict__ row,
                                               int* __restrict__ cur, int n) {
  __shared__ int part[1024];
  int t = threadIdx.x;
  int chunk = (n + 1023) >> 10;
  int beg = t * chunk;
  int end = min(beg + chunk, n);
  int s = 0;
  for (int i = beg; i < end; ++i) s += cnt[i];
  part[t] = s;
  __syncthreads();
  for (int d = 1; d < 1024; d <<= 1) {
    int v = (t >= d) ? part[t - d] : 0;
    __syncthreads();
    part[t] += v;
    __syncthreads();
  }
  int off = part[t] - s;  // exclusive
  for (int i = beg; i < end; ++i) {
    int c = cnt[i];
    row[i] = off;
    cur[i] = off;
    off += c;
  }
  if (t == 1023) row[n] = part[1023];
}

__global__ void k_scatter(const int* __restrict__ src, const int* __restrict__ dst,
                          int* __restrict__ cur, int* __restrict__ srcs, int E) {
  int e = blockIdx.x * 256 + threadIdx.x;
  if (e < E) {
    int d = dst[e];
    int pos = atomicAdd(&cur[d], 1);
    srcs[pos] = src[e];
  }
}

// ---------------- weight pre-pack: fp32 [K][64] -> fp16 B-fragments ----------------
// Bpack[(ct*nkk+kk)*64 + lane] (uint4 of 8 halfs): elem i = W[kk*32 + (lane>>4)*8 + i][ct*16 + (lane&15)]
// Same (lane-group, elem)->k map as the A-fragment loads, so the hardware k-permutation cancels.
__global__ __launch_bounds__(256) void k_wpack(const float* __restrict__ Wout,
                                               const float* __restrict__ W1,
                                               const float* __restrict__ W2,
                                               uint4* __restrict__ BoutP,
                                               uint4* __restrict__ B1P,
                                               uint4* __restrict__ B2P) {
  int t = blockIdx.x * 256 + threadIdx.x;  // 0..4095
  int layer = t >> 11;
  int r = t & 2047;
  const float* W;
  uint4* P;
  int idx, nkk;
  if (r < 1024) {
    W = Wout + layer * 128 * 64; P = BoutP + layer * 1024; idx = r; nkk = 4;
  } else if (r < 1536) {
    W = W1 + layer * 64 * 64; P = B1P + layer * 512; idx = r - 1024; nkk = 2;
  } else {
    W = W2 + layer * 64 * 64; P = B2P + layer * 512; idx = r - 1536; nkk = 2;
  }
  int lane = idx & 63;
  int ctkk = idx >> 6;
  int ct = ctkk / nkk, kk = ctkk - ct * nkk;
  int lc = lane & 15, lg = lane >> 4;
  unsigned short o[8];
#pragma unroll
  for (int i = 0; i < 8; ++i)
    o[i] = f2h(W[(kk * 32 + lg * 8 + i) * 64 + ct * 16 + lc]);
  P[idx] = *(const uint4*)o;
}

// ---------------- embedding: h = x @ emb_w + emb_b (32 nodes/block) ----------------
__global__ __launch_bounds__(256) void k_emb(const float* __restrict__ x,
                                             const float* __restrict__ w,
                                             const float* __restrict__ b,
                                             float* __restrict__ h, int n) {
  __shared__ float xs[32][DIN];
  int tid = threadIdx.x;
  int nb = blockIdx.x * 32;
  for (int t = tid; t < 32 * DIN; t += 256) {
    int ni = t >> 7, k = t & 127;
    int gn = nb + ni;
    xs[ni][k] = (gn < n) ? x[(size_t)gn * DIN + k] : 0.f;
  }
  __syncthreads();
  int col = tid & 63, grp = tid >> 6;  // 4 groups x 8 nodes
  float acc[8];
#pragma unroll
  for (int u = 0; u < 8; ++u) acc[u] = b[col];
  for (int k = 0; k < DIN; k += 4) {
    float w0 = w[k * 64 + col], w1 = w[(k + 1) * 64 + col];
    float w2 = w[(k + 2) * 64 + col], w3 = w[(k + 3) * 64 + col];
#pragma unroll
    for (int u = 0; u < 8; ++u) {
      float4 xv = *(const float4*)&xs[grp * 8 + u][k];
      acc[u] += xv.x * w0 + xv.y * w1 + xv.z * w2 + xv.w * w3;
    }
  }
#pragma unroll
  for (int u = 0; u < 8; ++u) {
    int gn = nb + grp * 8 + u;
    if (gn < n) h[(size_t)gn * 64 + col] = acc[u];
  }
}

// ---------------- QKV (32 nodes/block): Qh[N,128] (pre-scaled), KVh[N,256]=K|V, fp16 ----
__global__ __launch_bounds__(256) void k_qkv(const float* __restrict__ h,
                                             const float* __restrict__ Wq,
                                             const float* __restrict__ Wk,
                                             const float* __restrict__ Wv,
                                             unsigned short* __restrict__ Qh,
                                             unsigned short* __restrict__ KVh, int n) {
  __shared__ float hs[32][64];
  int tid = threadIdx.x;
  int nb = blockIdx.x * 32;
  for (int t = tid; t < 32 * 64; t += 256) {
    int ni = t >> 6, c = t & 63;
    int gn = nb + ni;
    hs[ni][c] = (gn < n) ? h[(size_t)gn * 64 + c] : 0.f;
  }
  __syncthreads();
  int j = tid & 127, grp = tid >> 7;  // 2 groups x 16 nodes
  float aq[16], ak[16], av[16];
#pragma unroll
  for (int u = 0; u < 16; ++u) aq[u] = ak[u] = av[u] = 0.f;
  for (int c = 0; c < 64; c += 4) {
    float wq0 = Wq[c * 128 + j], wq1 = Wq[(c + 1) * 128 + j];
    float wq2 = Wq[(c + 2) * 128 + j], wq3 = Wq[(c + 3) * 128 + j];
    float wk0 = Wk[c * 128 + j], wk1 = Wk[(c + 1) * 128 + j];
    float wk2 = Wk[(c + 2) * 128 + j], wk3 = Wk[(c + 3) * 128 + j];
    float wv0 = Wv[c * 128 + j], wv1 = Wv[(c + 1) * 128 + j];
    float wv2 = Wv[(c + 2) * 128 + j], wv3 = Wv[(c + 3) * 128 + j];
#pragma unroll
    for (int u = 0; u < 16; ++u) {
      float4 hv = *(const float4*)&hs[grp * 16 + u][c];
      aq[u] += hv.x * wq0 + hv.y * wq1 + hv.z * wq2 + hv.w * wq3;
      ak[u] += hv.x * wk0 + hv.y * wk1 + hv.z * wk2 + hv.w * wk3;
      av[u] += hv.x * wv0 + hv.y * wv1 + hv.z * wv2 + hv.w * wv3;
    }
  }
#pragma unroll
  for (int u = 0; u < 16; ++u) {
    int gn = nb + grp * 16 + u;
    if (gn < n) {
      Qh[(size_t)gn * 128 + j] = f2h(aq[u] * 0.125f);
      KVh[(size_t)gn * 256 + j] = f2h(ak[u]);
      KVh[(size_t)gn * 256 + 128 + j] = f2h(av[u]);
    }
  }
}

// ---------------- attention gather+softmax: aggrh[N,128] fp16 normalized ----------------
__global__ __launch_bounds__(256) void k_attn(
    const unsigned short* __restrict__ Qh, const unsigned short* __restrict__ KVh,
    const int* __restrict__ row, const int* __restrict__ srcs,
    unsigned short* __restrict__ aggrh, int n) {
  int lane = threadIdx.x & 63;
  int w = threadIdx.x >> 6;
  int node = blockIdx.x * 4 + w;
  if (node >= n) return;  // no barriers in this kernel
  int sl = lane & 15, gi = lane >> 4;

  uint4 qr = *(const uint4*)(Qh + (size_t)node * 128 + sl * 8);
  h2 q0 = bch2(qr.x), q1 = bch2(qr.y), q2 = bch2(qr.z), q3 = bch2(qr.w);

  int rs = row[node], re = row[node + 1];
  int deg = re - rs;
  float den = 0.f;
  h2 acc0 = {0, 0}, acc1 = {0, 0}, acc2 = {0, 0}, acc3 = {0, 0};

  if (deg > 0) {
    int iters = (deg + 3) >> 2;
    uint4 Kb[4], Vb[4];
    int sxb[4];
#pragma unroll
    for (int s = 0; s < 4; ++s) {
      if (s < iters) {
        int ei = rs + s * 4 + gi;
        int sx = (ei < re) ? srcs[ei] : srcs[rs];
        const unsigned short* kv = KVh + (size_t)sx * 256 + sl * 8;
        Kb[s] = *(const uint4*)kv;
        Vb[s] = *(const uint4*)(kv + 128);
      }
      int ei2 = rs + (s + 4) * 4 + gi;
      sxb[s] = (ei2 < re) ? srcs[ei2] : srcs[rs];
    }
    for (int it = 0; it < iters; it += 4) {
#pragma unroll
      for (int s = 0; s < 4; ++s) {
        int cit = it + s;
        if (cit < iters) {  // wave-uniform
          uint4 Kc = Kb[s], Vc = Vb[s];
          if (cit + 4 < iters) {
            const unsigned short* kv = KVh + (size_t)sxb[s] * 256 + sl * 8;
            Kb[s] = *(const uint4*)kv;
            Vb[s] = *(const uint4*)(kv + 128);
          }
          {
            int ei3 = rs + (cit + 8) * 4 + gi;
            sxb[s] = (ei3 < re) ? srcs[ei3] : srcs[rs];
          }
          float sc = __builtin_amdgcn_fdot2(bch2(Kc.x), q0, 0.f, false);
          sc = __builtin_amdgcn_fdot2(bch2(Kc.y), q1, sc, false);
          sc = __builtin_amdgcn_fdot2(bch2(Kc.z), q2, sc, false);
          sc = __builtin_amdgcn_fdot2(bch2(Kc.w), q3, sc, false);
          sc += __shfl_xor(sc, 1, 64);
          sc += __shfl_xor(sc, 2, 64);
          sc += __shfl_xor(sc, 4, 64);
          bool ev = (rs + cit * 4 + gi) < re;
          float wgt = ev ? __expf(sc) : 0.f;
          den += wgt;
          _Float16 wh = (_Float16)wgt;
          h2 W = {wh, wh};
          acc0 += W * bch2(Vc.x);
          acc1 += W * bch2(Vc.y);
          acc2 += W * bch2(Vc.z);
          acc3 += W * bch2(Vc.w);
        }
      }
    }
  }
#pragma unroll
  for (int d = 16; d < 64; d <<= 1) {
    den += __shfl_xor(den, d, 64);
    acc0 += h2shfl_xor(acc0, d);
    acc1 += h2shfl_xor(acc1, d);
    acc2 += h2shfl_xor(acc2, d);
    acc3 += h2shfl_xor(acc3, d);
  }
  float inv = fminf(1.f / (den + 1e-16f), 60000.f);
  if (lane < 16) {
    _Float16 ih = (_Float16)inv;
    h2 I = {ih, ih};
    uint4 o;
    o.x = h2u(acc0 * I);
    o.y = h2u(acc1 * I);
    o.z = h2u(acc2 * I);
    o.w = h2u(acc3 * I);
    *(uint4*)(aggrh + (size_t)node * 128 + sl * 8) = o;
  }
}

// ---------------- post (MFMA): Wout -> +res -> LN -> FFN. One 16-node tile per wave ----
// C/D layout (HW-verified): col = lane&15, row = (lane>>4)*4 + reg.
// VGPR-band lesson (r4-r6): scalar-FMA epilogues hoist 200+ weight loads -> 204-256 VGPR,
// 11% occupancy. MFMA form keeps ~32 MFMAs + small register state.
__global__ __launch_bounds__(256) void k_post(
    const unsigned short* __restrict__ aggrh, float* __restrict__ h,
    const uint4* __restrict__ Bout, const float* __restrict__ bout,
    const float* __restrict__ lng, const float* __restrict__ lnb,
    const uint4* __restrict__ B1, const float* __restrict__ b1,
    const uint4* __restrict__ B2, const float* __restrict__ b2, int n) {
  __shared__ unsigned short red[4][16 * 88];  // per-wave A-redistribution buffer (fp16)
  int lane = threadIdx.x & 63, wv = threadIdx.x >> 6;
  int nb = (blockIdx.x * 4 + wv) * 16;
  if (nb >= n) return;  // no barriers in this kernel
  int lc = lane & 15, lg = lane >> 4;

  // GEMM1: O[16,64] = aggr[16,128] @ Wout
  f32x4 acc[4] = {{0, 0, 0, 0}, {0, 0, 0, 0}, {0, 0, 0, 0}, {0, 0, 0, 0}};
  const uint4* arow_p = (const uint4*)(aggrh + (size_t)(nb + lc) * 128);
#pragma unroll
  for (int kk = 0; kk < 4; ++kk) {
    f16x8 af = bcf16x8(arow_p[kk * 4 + lg]);
#pragma unroll
    for (int ct = 0; ct < 4; ++ct)
      acc[ct] = __builtin_amdgcn_mfma_f32_16x16x32_f16(
          af, bcf16x8(Bout[(ct * 4 + kk) * 64 + lane]), acc[ct], 0, 0, 0);
  }

  // bias + residual + layernorm (rows r = lg*4+0..3, cols ct*16+lc)
  float x[4][4], hl[4][4];  // [r][ct]
#pragma unroll
  for (int ct = 0; ct < 4; ++ct) {
    float bo = bout[ct * 16 + lc];
#pragma unroll
    for (int r = 0; r < 4; ++r)
      x[r][ct] = acc[ct][r] + bo + h[(size_t)(nb + lg * 4 + r) * 64 + ct * 16 + lc];
  }
  float g[4], bb[4];
#pragma unroll
  for (int ct = 0; ct < 4; ++ct) {
    g[ct] = lng[ct * 16 + lc];
    bb[ct] = lnb[ct * 16 + lc];
  }
#pragma unroll
  for (int r = 0; r < 4; ++r) {
    float s = x[r][0] + x[r][1] + x[r][2] + x[r][3];
    s += __shfl_xor(s, 1, 64);
    s += __shfl_xor(s, 2, 64);
    s += __shfl_xor(s, 4, 64);
    s += __shfl_xor(s, 8, 64);
    float mu = s * (1.f / 64.f);
    float s2 = 0.f;
#pragma unroll
    for (int ct = 0; ct < 4; ++ct) {
      float xc = x[r][ct] - mu;
      s2 += xc * xc;
    }
    s2 += __shfl_xor(s2, 1, 64);
    s2 += __shfl_xor(s2, 2, 64);
    s2 += __shfl_xor(s2, 4, 64);
    s2 += __shfl_xor(s2, 8, 64);
    float inv = rsqrtf(s2 * (1.f / 64.f) + 1e-5f);
#pragma unroll
    for (int ct = 0; ct < 4; ++ct) {
      hl[r][ct] = (x[r][ct] - mu) * inv * g[ct] + bb[ct];
      red[wv][(lg * 4 + r) * 88 + ct * 16 + lc] = f2h(hl[r][ct]);
    }
  }

  // GEMM2: T = relu(hl @ W1 + b1)
  f32x4 acc2[4] = {{0, 0, 0, 0}, {0, 0, 0, 0}, {0, 0, 0, 0}, {0, 0, 0, 0}};
#pragma unroll
  for (int kk = 0; kk < 2; ++kk) {
    f16x8 af = bcf16x8(*(const uint4*)&red[wv][lc * 88 + kk * 32 + lg * 8]);
#pragma unroll
    for (int ct = 0; ct < 4; ++ct)
      acc2[ct] = __builtin_amdgcn_mfma_f32_16x16x32_f16(
          af, bcf16x8(B1[(ct * 2 + kk) * 64 + lane]), acc2[ct], 0, 0, 0);
  }
#pragma unroll
  for (int ct = 0; ct < 4; ++ct) {
    float b1c = b1[ct * 16 + lc];
#pragma unroll
    for (int r = 0; r < 4; ++r)
      red[wv][(lg * 4 + r) * 88 + ct * 16 + lc] = f2h(fmaxf(acc2[ct][r] + b1c, 0.f));
  }

  // GEMM3: out = hl + T @ W2 + b2
  f32x4 acc3[4] = {{0, 0, 0, 0}, {0, 0, 0, 0}, {0, 0, 0, 0}, {0, 0, 0, 0}};
#pragma unroll
  for (int kk = 0; kk < 2; ++kk) {
    f16x8 af = bcf16x8(*(const uint4*)&red[wv][lc * 88 + kk * 32 + lg * 8]);
#pragma unroll
    for (int ct = 0; ct < 4; ++ct)
      acc3[ct] = __builtin_amdgcn_mfma_f32_16x16x32_f16(
          af, bcf16x8(B2[(ct * 2 + kk) * 64 + lane]), acc3[ct], 0, 0, 0);
  }
#pragma unroll
  for (int ct = 0; ct < 4; ++ct) {
    float b2c = b2[ct * 16 + lc];
#pragma unroll
    for (int r = 0; r < 4; ++r) {
      int gn = nb + lg * 4 + r;
      if (gn < n) h[(size_t)gn * 64 + ct * 16 + lc] = hl[r][ct] + acc3[ct][r] + b2c;
    }
  }
}

// ---------------- output: log_softmax(h @ out_w + out_b) (16 nodes/block) ----------------
__global__ __launch_bounds__(256) void k_out(const float* __restrict__ h,
                                             const float* __restrict__ w,
                                             const float* __restrict__ b,
                                             float* __restrict__ out, int n) {
  __shared__ float s_h[16][64];
  int tid = threadIdx.x;
  int nb = blockIdx.x * 16;
  for (int t = tid; t < 16 * 64; t += 256) {
    int ni = t >> 6;
    int gn = nb + ni;
    s_h[ni][t & 63] = (gn < n) ? h[(size_t)gn * 64 + (t & 63)] : 0.f;
  }
  __syncthreads();
  int lane = tid & 63, wv = tid >> 6;
  for (int u = 0; u < 4; ++u) {
    int li = wv * 4 + u;
    int node = nb + li;
    float lv = -3.0e38f;
    if (lane < 40) {
      lv = b[lane];
#pragma unroll 8
      for (int j = 0; j < 64; ++j) lv += s_h[li][j] * w[j * 40 + lane];
    }
    float m = wred_max(lv);
    float ex = (lane < 40) ? __expf(lv - m) : 0.f;
    float s = wred_sum(ex);
    if (node < n && lane < 40) out[(size_t)node * 40 + lane] = lv - m - logf(s);
  }
}

extern "C" void kernel_launch(void* const* d_in, const int* in_sizes, int n_in,
                              void* d_out, int out_size, void* d_ws, size_t ws_size,
                              hipStream_t stream) {
  const float* x     = (const float*)d_in[0];
  const int*   ei    = (const int*)d_in[1];
  const float* emb_w = (const float*)d_in[2];
  const float* emb_b = (const float*)d_in[3];
  const float* Wq    = (const float*)d_in[4];   // [2,64,128]
  const float* Wk    = (const float*)d_in[5];
  const float* Wv    = (const float*)d_in[6];
  const float* Wout  = (const float*)d_in[7];   // [2,128,64]
  const float* bout  = (const float*)d_in[8];
  const float* ln_g  = (const float*)d_in[9];
  const float* ln_b  = (const float*)d_in[10];
  const float* W1    = (const float*)d_in[11];  // [2,64,64]
  const float* b1    = (const float*)d_in[12];
  const float* W2    = (const float*)d_in[13];
  const float* b2    = (const float*)d_in[14];
  const float* out_w = (const float*)d_in[15];  // [64,40]
  const float* out_b = (const float*)d_in[16];
  float* out = (float*)d_out;

  const int n = in_sizes[0] / DIN;  // 50000
  const int E = in_sizes[1] / 2;    // 800000

  char* ws = (char*)d_ws;
  size_t off = 0;
  auto alloc = [&](size_t bytes) {
    void* p = ws + off;
    off = (off + bytes + 255) & ~(size_t)255;
    return p;
  };
  float* h              = (float*)alloc((size_t)n * 64 * 4);
  unsigned short* Qh    = (unsigned short*)alloc((size_t)n * 128 * 2);
  unsigned short* KVh   = (unsigned short*)alloc((size_t)n * 256 * 2);
  unsigned short* aggrh = (unsigned short*)alloc((size_t)n * 128 * 2);
  int* cnt              = (int*)alloc((size_t)n * 4);
  int* rowp             = (int*)alloc((size_t)(n + 1) * 4);
  int* cur              = (int*)alloc((size_t)n * 4);
  int* srcs             = (int*)alloc((size_t)E * 4);
  uint4* BoutP          = (uint4*)alloc((size_t)2 * 1024 * 16);
  uint4* B1P            = (uint4*)alloc((size_t)2 * 512 * 16);
  uint4* B2P            = (uint4*)alloc((size_t)2 * 512 * 16);

  const int* src = ei;
  const int* dst = ei + E;

  hipMemsetAsync(cnt, 0, (size_t)n * 4, stream);
  k_hist<<<(E + 255) / 256, 256, 0, stream>>>(dst, cnt, E);
  k_scan<<<1, 1024, 0, stream>>>(cnt, rowp, cur, n);
  k_scatter<<<(E + 255) / 256, 256, 0, stream>>>(src, dst, cur, srcs, E);

  k_wpack<<<16, 256, 0, stream>>>(Wout, W1, W2, BoutP, B1P, B2P);
  k_emb<<<(n + 31) / 32, 256, 0, stream>>>(x, emb_w, emb_b, h, n);

  for (int l = 0; l < 2; ++l) {
    k_qkv<<<(n + 31) / 32, 256, 0, stream>>>(h, Wq + (size_t)l * 64 * 128,
                                             Wk + (size_t)l * 64 * 128,
                                             Wv + (size_t)l * 64 * 128, Qh, KVh, n);
    k_attn<<<(n + 3) / 4, 256, 0, stream>>>(Qh, KVh, rowp, srcs, aggrh, n);
    k_post<<<(n + 63) / 64, 256, 0, stream>>>(
        aggrh, h, BoutP + (size_t)l * 1024, bout + (size_t)l * 64,
        ln_g + (size_t)l * 64, ln_b + (size_t)l * 64, B1P + (size_t)l * 512,
        b1 + (size_t)l * 64, B2P + (size_t)l * 512, b2 + (size_t)l * 64, n);
  }

  k_out<<<(n + 15) / 16, 256, 0, stream>>>(h, out_w, out_b, out, n);
}

// Round 8
// 411.730 us; speedup vs baseline: 7.7062x; 1.2347x over previous
//
#include <hip/hip_runtime.h>
#include <math.h>

#define DIN 128
#define HID 64

typedef _Float16 h2 __attribute__((ext_vector_type(2)));
typedef _Float16 f16x8 __attribute__((ext_vector_type(8)));
typedef float f32x4 __attribute__((ext_vector_type(4)));

__device__ inline float wred_sum(float v) {
#pragma unroll
  for (int d = 1; d < 64; d <<= 1) v += __shfl_xor(v, d, 64);
  return v;
}
__device__ inline float wred_max(float v) {
#pragma unroll
  for (int d = 1; d < 64; d <<= 1) v = fmaxf(v, __shfl_xor(v, d, 64));
  return v;
}
__device__ inline unsigned short f2h(float f) {
  return __builtin_bit_cast(unsigned short, (_Float16)f);
}
__device__ inline h2 bch2(unsigned int u) { return __builtin_bit_cast(h2, u); }
__device__ inline unsigned int h2u(h2 x) { return __builtin_bit_cast(unsigned int, x); }
__device__ inline f16x8 bcf16x8(uint4 u) { return __builtin_bit_cast(f16x8, u); }
__device__ inline h2 h2shfl_xor(h2 x, int d) {
  int xi = __builtin_bit_cast(int, x);
  xi = __shfl_xor(xi, d, 64);
  return __builtin_bit_cast(h2, xi);
}

// ---------------- CSR build ----------------
__global__ void k_hist(const int* __restrict__ dst, int* __restrict__ cnt, int E) {
  int e = blockIdx.x * 256 + threadIdx.x;
  if (e < E) atomicAdd(&cnt[dst[e]], 1);
}

// 3-phase multi-block scan (r7: single-block scan was 111 us on one CU)
__global__ __launch_bounds__(256) void k_scanA(const int* __restrict__ cnt,
                                               int* __restrict__ bsum, int n) {
  int tid = threadIdx.x;
  int base = blockIdx.x * 2048 + tid * 8;
  int s = 0;
#pragma unroll
  for (int i = 0; i < 8; ++i) {
    int idx = base + i;
    if (idx < n) s += cnt[idx];
  }
#pragma unroll
  for (int d = 1; d < 64; d <<= 1) s += __shfl_xor(s, d, 64);
  __shared__ int sm[4];
  int lane = tid & 63, wv = tid >> 6;
  if (lane == 0) sm[wv] = s;
  __syncthreads();
  if (tid == 0) bsum[blockIdx.x] = sm[0] + sm[1] + sm[2] + sm[3];
}

__global__ void k_scanB(const int* __restrict__ bsum, int* __restrict__ boff,
                        int* __restrict__ row, int nblk, int n) {
  if (threadIdx.x == 0 && blockIdx.x == 0) {
    int acc = 0;
    for (int i = 0; i < nblk; ++i) {
      boff[i] = acc;
      acc += bsum[i];
    }
    row[n] = acc;
  }
}

__global__ __launch_bounds__(256) void k_scanC(const int* __restrict__ cnt,
                                               const int* __restrict__ boff,
                                               int* __restrict__ row,
                                               int* __restrict__ cur, int n) {
  int tid = threadIdx.x;
  int lane = tid & 63, wv = tid >> 6;
  int base = blockIdx.x * 2048 + tid * 8;
  int v[8];
  int s = 0;
#pragma unroll
  for (int i = 0; i < 8; ++i) {
    int idx = base + i;
    v[i] = (idx < n) ? cnt[idx] : 0;
    s += v[i];
  }
  int incl = s;
#pragma unroll
  for (int d = 1; d < 64; d <<= 1) {
    int t = __shfl_up(incl, d, 64);
    if (lane >= d) incl += t;
  }
  __shared__ int wsum[4];
  if (lane == 63) wsum[wv] = incl;
  __syncthreads();
  int woff = 0;
  for (int i = 0; i < wv; ++i) woff += wsum[i];
  int excl = incl - s + woff + boff[blockIdx.x];
#pragma unroll
  for (int i = 0; i < 8; ++i) {
    int idx = base + i;
    if (idx < n) {
      row[idx] = excl;
      cur[idx] = excl;
      excl += v[i];
    }
  }
}

__global__ void k_scatter(const int* __restrict__ src, const int* __restrict__ dst,
                          int* __restrict__ cur, int* __restrict__ srcs, int E) {
  int e = blockIdx.x * 256 + threadIdx.x;
  if (e < E) {
    int d = dst[e];
    int pos = atomicAdd(&cur[d], 1);
    srcs[pos] = src[e];
  }
}

// ---------------- weight pre-pack: fp32 [K][64] -> fp16 B-fragments ----------------
__global__ __launch_bounds__(256) void k_wpack(const float* __restrict__ Wout,
                                               const float* __restrict__ W1,
                                               const float* __restrict__ W2,
                                               uint4* __restrict__ BoutP,
                                               uint4* __restrict__ B1P,
                                               uint4* __restrict__ B2P) {
  int t = blockIdx.x * 256 + threadIdx.x;  // 0..4095
  int layer = t >> 11;
  int r = t & 2047;
  const float* W;
  uint4* P;
  int idx, nkk;
  if (r < 1024) {
    W = Wout + layer * 128 * 64; P = BoutP + layer * 1024; idx = r; nkk = 4;
  } else if (r < 1536) {
    W = W1 + layer * 64 * 64; P = B1P + layer * 512; idx = r - 1024; nkk = 2;
  } else {
    W = W2 + layer * 64 * 64; P = B2P + layer * 512; idx = r - 1536; nkk = 2;
  }
  int lane = idx & 63;
  int ctkk = idx >> 6;
  int ct = ctkk / nkk, kk = ctkk - ct * nkk;
  int lc = lane & 15, lg = lane >> 4;
  unsigned short o[8];
#pragma unroll
  for (int i = 0; i < 8; ++i)
    o[i] = f2h(W[(kk * 32 + lg * 8 + i) * 64 + ct * 16 + lc]);
  P[idx] = *(const uint4*)o;
}

// ---------------- embedding: h = x @ emb_w + emb_b (32 nodes/block) ----------------
__global__ __launch_bounds__(256) void k_emb(const float* __restrict__ x,
                                             const float* __restrict__ w,
                                             const float* __restrict__ b,
                                             float* __restrict__ h, int n) {
  __shared__ float xs[32][DIN];
  int tid = threadIdx.x;
  int nb = blockIdx.x * 32;
  for (int t = tid; t < 32 * DIN; t += 256) {
    int ni = t >> 7, k = t & 127;
    int gn = nb + ni;
    xs[ni][k] = (gn < n) ? x[(size_t)gn * DIN + k] : 0.f;
  }
  __syncthreads();
  int col = tid & 63, grp = tid >> 6;  // 4 groups x 8 nodes
  float acc[8];
#pragma unroll
  for (int u = 0; u < 8; ++u) acc[u] = b[col];
  for (int k = 0; k < DIN; k += 4) {
    float w0 = w[k * 64 + col], w1 = w[(k + 1) * 64 + col];
    float w2 = w[(k + 2) * 64 + col], w3 = w[(k + 3) * 64 + col];
#pragma unroll
    for (int u = 0; u < 8; ++u) {
      float4 xv = *(const float4*)&xs[grp * 8 + u][k];
      acc[u] += xv.x * w0 + xv.y * w1 + xv.z * w2 + xv.w * w3;
    }
  }
#pragma unroll
  for (int u = 0; u < 8; ++u) {
    int gn = nb + grp * 8 + u;
    if (gn < n) h[(size_t)gn * 64 + col] = acc[u];
  }
}

// ---------------- QKV (32 nodes/block): Qh[N,128] (pre-scaled), KVh[N,256]=K|V, fp16 ----
__global__ __launch_bounds__(256) void k_qkv(const float* __restrict__ h,
                                             const float* __restrict__ Wq,
                                             const float* __restrict__ Wk,
                                             const float* __restrict__ Wv,
                                             unsigned short* __restrict__ Qh,
                                             unsigned short* __restrict__ KVh, int n) {
  __shared__ float hs[32][64];
  int tid = threadIdx.x;
  int nb = blockIdx.x * 32;
  for (int t = tid; t < 32 * 64; t += 256) {
    int ni = t >> 6, c = t & 63;
    int gn = nb + ni;
    hs[ni][c] = (gn < n) ? h[(size_t)gn * 64 + c] : 0.f;
  }
  __syncthreads();
  int j = tid & 127, grp = tid >> 7;  // 2 groups x 16 nodes
  float aq[16], ak[16], av[16];
#pragma unroll
  for (int u = 0; u < 16; ++u) aq[u] = ak[u] = av[u] = 0.f;
  for (int c = 0; c < 64; c += 4) {
    float wq0 = Wq[c * 128 + j], wq1 = Wq[(c + 1) * 128 + j];
    float wq2 = Wq[(c + 2) * 128 + j], wq3 = Wq[(c + 3) * 128 + j];
    float wk0 = Wk[c * 128 + j], wk1 = Wk[(c + 1) * 128 + j];
    float wk2 = Wk[(c + 2) * 128 + j], wk3 = Wk[(c + 3) * 128 + j];
    float wv0 = Wv[c * 128 + j], wv1 = Wv[(c + 1) * 128 + j];
    float wv2 = Wv[(c + 2) * 128 + j], wv3 = Wv[(c + 3) * 128 + j];
#pragma unroll
    for (int u = 0; u < 16; ++u) {
      float4 hv = *(const float4*)&hs[grp * 16 + u][c];
      aq[u] += hv.x * wq0 + hv.y * wq1 + hv.z * wq2 + hv.w * wq3;
      ak[u] += hv.x * wk0 + hv.y * wk1 + hv.z * wk2 + hv.w * wk3;
      av[u] += hv.x * wv0 + hv.y * wv1 + hv.z * wv2 + hv.w * wv3;
    }
  }
#pragma unroll
  for (int u = 0; u < 16; ++u) {
    int gn = nb + grp * 16 + u;
    if (gn < n) {
      Qh[(size_t)gn * 128 + j] = f2h(aq[u] * 0.125f);
      KVh[(size_t)gn * 256 + j] = f2h(ak[u]);
      KVh[(size_t)gn * 256 + 128 + j] = f2h(av[u]);
    }
  }
}

// ---------------- attention gather+softmax: aggrh[N,128] fp16 normalized ----------------
__global__ __launch_bounds__(256) void k_attn(
    const unsigned short* __restrict__ Qh, const unsigned short* __restrict__ KVh,
    const int* __restrict__ row, const int* __restrict__ srcs,
    unsigned short* __restrict__ aggrh, int n) {
  int lane = threadIdx.x & 63;
  int w = threadIdx.x >> 6;
  int node = blockIdx.x * 4 + w;
  if (node >= n) return;  // no barriers in this kernel
  int sl = lane & 15, gi = lane >> 4;

  uint4 qr = *(const uint4*)(Qh + (size_t)node * 128 + sl * 8);
  h2 q0 = bch2(qr.x), q1 = bch2(qr.y), q2 = bch2(qr.z), q3 = bch2(qr.w);

  int rs = row[node], re = row[node + 1];
  int deg = re - rs;
  float den = 0.f;
  h2 acc0 = {0, 0}, acc1 = {0, 0}, acc2 = {0, 0}, acc3 = {0, 0};

  if (deg > 0) {
    int iters = (deg + 3) >> 2;
    uint4 Kb[4], Vb[4];
    int sxb[4];
#pragma unroll
    for (int s = 0; s < 4; ++s) {
      if (s < iters) {
        int ei = rs + s * 4 + gi;
        int sx = (ei < re) ? srcs[ei] : srcs[rs];
        const unsigned short* kv = KVh + (size_t)sx * 256 + sl * 8;
        Kb[s] = *(const uint4*)kv;
        Vb[s] = *(const uint4*)(kv + 128);
      }
      int ei2 = rs + (s + 4) * 4 + gi;
      sxb[s] = (ei2 < re) ? srcs[ei2] : srcs[rs];
    }
    for (int it = 0; it < iters; it += 4) {
#pragma unroll
      for (int s = 0; s < 4; ++s) {
        int cit = it + s;
        if (cit < iters) {  // wave-uniform
          uint4 Kc = Kb[s], Vc = Vb[s];
          if (cit + 4 < iters) {
            const unsigned short* kv = KVh + (size_t)sxb[s] * 256 + sl * 8;
            Kb[s] = *(const uint4*)kv;
            Vb[s] = *(const uint4*)(kv + 128);
          }
          {
            int ei3 = rs + (cit + 8) * 4 + gi;
            sxb[s] = (ei3 < re) ? srcs[ei3] : srcs[rs];
          }
          float sc = __builtin_amdgcn_fdot2(bch2(Kc.x), q0, 0.f, false);
          sc = __builtin_amdgcn_fdot2(bch2(Kc.y), q1, sc, false);
          sc = __builtin_amdgcn_fdot2(bch2(Kc.z), q2, sc, false);
          sc = __builtin_amdgcn_fdot2(bch2(Kc.w), q3, sc, false);
          sc += __shfl_xor(sc, 1, 64);
          sc += __shfl_xor(sc, 2, 64);
          sc += __shfl_xor(sc, 4, 64);
          bool ev = (rs + cit * 4 + gi) < re;
          float wgt = ev ? __expf(sc) : 0.f;
          den += wgt;
          _Float16 wh = (_Float16)wgt;
          h2 W = {wh, wh};
          acc0 += W * bch2(Vc.x);
          acc1 += W * bch2(Vc.y);
          acc2 += W * bch2(Vc.z);
          acc3 += W * bch2(Vc.w);
        }
      }
    }
  }
#pragma unroll
  for (int d = 16; d < 64; d <<= 1) {
    den += __shfl_xor(den, d, 64);
    acc0 += h2shfl_xor(acc0, d);
    acc1 += h2shfl_xor(acc1, d);
    acc2 += h2shfl_xor(acc2, d);
    acc3 += h2shfl_xor(acc3, d);
  }
  float inv = fminf(1.f / (den + 1e-16f), 60000.f);
  if (lane < 16) {
    _Float16 ih = (_Float16)inv;
    h2 I = {ih, ih};
    uint4 o;
    o.x = h2u(acc0 * I);
    o.y = h2u(acc1 * I);
    o.z = h2u(acc2 * I);
    o.w = h2u(acc3 * I);
    *(uint4*)(aggrh + (size_t)node * 128 + sl * 8) = o;
  }
}

// ---------------- post (MFMA): Wout -> +res -> LN -> FFN. One 16-node tile per wave ----
// C/D layout (HW-verified): col = lane&15, row = (lane>>4)*4 + reg.
__global__ __launch_bounds__(256) void k_post(
    const unsigned short* __restrict__ aggrh, float* __restrict__ h,
    const uint4* __restrict__ Bout, const float* __restrict__ bout,
    const float* __restrict__ lng, const float* __restrict__ lnb,
    const uint4* __restrict__ B1, const float* __restrict__ b1,
    const uint4* __restrict__ B2, const float* __restrict__ b2, int n) {
  __shared__ unsigned short red[4][16 * 88];  // per-wave A-redistribution buffer (fp16)
  int lane = threadIdx.x & 63, wv = threadIdx.x >> 6;
  int nb = (blockIdx.x * 4 + wv) * 16;
  if (nb >= n) return;  // no barriers in this kernel
  int lc = lane & 15, lg = lane >> 4;

  // GEMM1: O[16,64] = aggr[16,128] @ Wout
  f32x4 acc[4] = {{0, 0, 0, 0}, {0, 0, 0, 0}, {0, 0, 0, 0}, {0, 0, 0, 0}};
  const uint4* arow_p = (const uint4*)(aggrh + (size_t)(nb + lc) * 128);
#pragma unroll
  for (int kk = 0; kk < 4; ++kk) {
    f16x8 af = bcf16x8(arow_p[kk * 4 + lg]);
#pragma unroll
    for (int ct = 0; ct < 4; ++ct)
      acc[ct] = __builtin_amdgcn_mfma_f32_16x16x32_f16(
          af, bcf16x8(Bout[(ct * 4 + kk) * 64 + lane]), acc[ct], 0, 0, 0);
  }

  // bias + residual + layernorm (rows r = lg*4+0..3, cols ct*16+lc)
  float x[4][4], hl[4][4];  // [r][ct]
#pragma unroll
  for (int ct = 0; ct < 4; ++ct) {
    float bo = bout[ct * 16 + lc];
#pragma unroll
    for (int r = 0; r < 4; ++r)
      x[r][ct] = acc[ct][r] + bo + h[(size_t)(nb + lg * 4 + r) * 64 + ct * 16 + lc];
  }
  float g[4], bb[4];
#pragma unroll
  for (int ct = 0; ct < 4; ++ct) {
    g[ct] = lng[ct * 16 + lc];
    bb[ct] = lnb[ct * 16 + lc];
  }
#pragma unroll
  for (int r = 0; r < 4; ++r) {
    float s = x[r][0] + x[r][1] + x[r][2] + x[r][3];
    s += __shfl_xor(s, 1, 64);
    s += __shfl_xor(s, 2, 64);
    s += __shfl_xor(s, 4, 64);
    s += __shfl_xor(s, 8, 64);
    float mu = s * (1.f / 64.f);
    float s2 = 0.f;
#pragma unroll
    for (int ct = 0; ct < 4; ++ct) {
      float xc = x[r][ct] - mu;
      s2 += xc * xc;
    }
    s2 += __shfl_xor(s2, 1, 64);
    s2 += __shfl_xor(s2, 2, 64);
    s2 += __shfl_xor(s2, 4, 64);
    s2 += __shfl_xor(s2, 8, 64);
    float inv = rsqrtf(s2 * (1.f / 64.f) + 1e-5f);
#pragma unroll
    for (int ct = 0; ct < 4; ++ct) {
      hl[r][ct] = (x[r][ct] - mu) * inv * g[ct] + bb[ct];
      red[wv][(lg * 4 + r) * 88 + ct * 16 + lc] = f2h(hl[r][ct]);
    }
  }

  // GEMM2: T = relu(hl @ W1 + b1)
  f32x4 acc2[4] = {{0, 0, 0, 0}, {0, 0, 0, 0}, {0, 0, 0, 0}, {0, 0, 0, 0}};
#pragma unroll
  for (int kk = 0; kk < 2; ++kk) {
    f16x8 af = bcf16x8(*(const uint4*)&red[wv][lc * 88 + kk * 32 + lg * 8]);
#pragma unroll
    for (int ct = 0; ct < 4; ++ct)
      acc2[ct] = __builtin_amdgcn_mfma_f32_16x16x32_f16(
          af, bcf16x8(B1[(ct * 2 + kk) * 64 + lane]), acc2[ct], 0, 0, 0);
  }
#pragma unroll
  for (int ct = 0; ct < 4; ++ct) {
    float b1c = b1[ct * 16 + lc];
#pragma unroll
    for (int r = 0; r < 4; ++r)
      red[wv][(lg * 4 + r) * 88 + ct * 16 + lc] = f2h(fmaxf(acc2[ct][r] + b1c, 0.f));
  }

  // GEMM3: out = hl + T @ W2 + b2
  f32x4 acc3[4] = {{0, 0, 0, 0}, {0, 0, 0, 0}, {0, 0, 0, 0}, {0, 0, 0, 0}};
#pragma unroll
  for (int kk = 0; kk < 2; ++kk) {
    f16x8 af = bcf16x8(*(const uint4*)&red[wv][lc * 88 + kk * 32 + lg * 8]);
#pragma unroll
    for (int ct = 0; ct < 4; ++ct)
      acc3[ct] = __builtin_amdgcn_mfma_f32_16x16x32_f16(
          af, bcf16x8(B2[(ct * 2 + kk) * 64 + lane]), acc3[ct], 0, 0, 0);
  }
#pragma unroll
  for (int ct = 0; ct < 4; ++ct) {
    float b2c = b2[ct * 16 + lc];
#pragma unroll
    for (int r = 0; r < 4; ++r) {
      int gn = nb + lg * 4 + r;
      if (gn < n) h[(size_t)gn * 64 + ct * 16 + lc] = hl[r][ct] + acc3[ct][r] + b2c;
    }
  }
}

// ---------------- output: log_softmax(h @ out_w + out_b) (16 nodes/block) ----------------
__global__ __launch_bounds__(256) void k_out(const float* __restrict__ h,
                                             const float* __restrict__ w,
                                             const float* __restrict__ b,
                                             float* __restrict__ out, int n) {
  __shared__ float s_h[16][64];
  int tid = threadIdx.x;
  int nb = blockIdx.x * 16;
  for (int t = tid; t < 16 * 64; t += 256) {
    int ni = t >> 6;
    int gn = nb + ni;
    s_h[ni][t & 63] = (gn < n) ? h[(size_t)gn * 64 + (t & 63)] : 0.f;
  }
  __syncthreads();
  int lane = tid & 63, wv = tid >> 6;
  for (int u = 0; u < 4; ++u) {
    int li = wv * 4 + u;
    int node = nb + li;
    float lv = -3.0e38f;
    if (lane < 40) {
      lv = b[lane];
#pragma unroll 8
      for (int j = 0; j < 64; ++j) lv += s_h[li][j] * w[j * 40 + lane];
    }
    float m = wred_max(lv);
    float ex = (lane < 40) ? __expf(lv - m) : 0.f;
    float s = wred_sum(ex);
    if (node < n && lane < 40) out[(size_t)node * 40 + lane] = lv - m - logf(s);
  }
}

extern "C" void kernel_launch(void* const* d_in, const int* in_sizes, int n_in,
                              void* d_out, int out_size, void* d_ws, size_t ws_size,
                              hipStream_t stream) {
  const float* x     = (const float*)d_in[0];
  const int*   ei    = (const int*)d_in[1];
  const float* emb_w = (const float*)d_in[2];
  const float* emb_b = (const float*)d_in[3];
  const float* Wq    = (const float*)d_in[4];   // [2,64,128]
  const float* Wk    = (const float*)d_in[5];
  const float* Wv    = (const float*)d_in[6];
  const float* Wout  = (const float*)d_in[7];   // [2,128,64]
  const float* bout  = (const float*)d_in[8];
  const float* ln_g  = (const float*)d_in[9];
  const float* ln_b  = (const float*)d_in[10];
  const float* W1    = (const float*)d_in[11];  // [2,64,64]
  const float* b1    = (const float*)d_in[12];
  const float* W2    = (const float*)d_in[13];
  const float* b2    = (const float*)d_in[14];
  const float* out_w = (const float*)d_in[15];  // [64,40]
  const float* out_b = (const float*)d_in[16];
  float* out = (float*)d_out;

  const int n = in_sizes[0] / DIN;  // 50000
  const int E = in_sizes[1] / 2;    // 800000

  char* ws = (char*)d_ws;
  size_t off = 0;
  auto alloc = [&](size_t bytes) {
    void* p = ws + off;
    off = (off + bytes + 255) & ~(size_t)255;
    return p;
  };
  float* h              = (float*)alloc((size_t)n * 64 * 4);
  unsigned short* Qh    = (unsigned short*)alloc((size_t)n * 128 * 2);
  unsigned short* KVh   = (unsigned short*)alloc((size_t)n * 256 * 2);
  unsigned short* aggrh = (unsigned short*)alloc((size_t)n * 128 * 2);
  int* cnt              = (int*)alloc((size_t)n * 4);
  int* rowp             = (int*)alloc((size_t)(n + 1) * 4);
  int* cur              = (int*)alloc((size_t)n * 4);
  int* srcs             = (int*)alloc((size_t)E * 4);
  uint4* BoutP          = (uint4*)alloc((size_t)2 * 1024 * 16);
  uint4* B1P            = (uint4*)alloc((size_t)2 * 512 * 16);
  uint4* B2P            = (uint4*)alloc((size_t)2 * 512 * 16);
  int nScanBlk          = (n + 2047) / 2048;
  int* bsum             = (int*)alloc((size_t)nScanBlk * 4);
  int* boff             = (int*)alloc((size_t)nScanBlk * 4);

  const int* src = ei;
  const int* dst = ei + E;

  hipMemsetAsync(cnt, 0, (size_t)n * 4, stream);
  k_hist<<<(E + 255) / 256, 256, 0, stream>>>(dst, cnt, E);
  k_scanA<<<nScanBlk, 256, 0, stream>>>(cnt, bsum, n);
  k_scanB<<<1, 64, 0, stream>>>(bsum, boff, rowp, nScanBlk, n);
  k_scanC<<<nScanBlk, 256, 0, stream>>>(cnt, boff, rowp, cur, n);
  k_scatter<<<(E + 255) / 256, 256, 0, stream>>>(src, dst, cur, srcs, E);

  k_wpack<<<16, 256, 0, stream>>>(Wout, W1, W2, BoutP, B1P, B2P);
  k_emb<<<(n + 31) / 32, 256, 0, stream>>>(x, emb_w, emb_b, h, n);

  for (int l = 0; l < 2; ++l) {
    k_qkv<<<(n + 31) / 32, 256, 0, stream>>>(h, Wq + (size_t)l * 64 * 128,
                                             Wk + (size_t)l * 64 * 128,
                                             Wv + (size_t)l * 64 * 128, Qh, KVh, n);
    k_attn<<<(n + 3) / 4, 256, 0, stream>>>(Qh, KVh, rowp, srcs, aggrh, n);
    k_post<<<(n + 63) / 64, 256, 0, stream>>>(
        aggrh, h, BoutP + (size_t)l * 1024, bout + (size_t)l * 64,
        ln_g + (size_t)l * 64, ln_b + (size_t)l * 64, B1P + (size_t)l * 512,
        b1 + (size_t)l * 64, B2P + (size_t)l * 512, b2 + (size_t)l * 64, n);
  }

  k_out<<<(n + 15) / 16, 256, 0, stream>>>(h, out_w, out_b, out, n);
}

// Round 9
// 342.928 us; speedup vs baseline: 9.2524x; 1.2006x over previous
//
#include <hip/hip_runtime.h>
#include <math.h>

#define DIN 128
#define HID 64

typedef _Float16 h2 __attribute__((ext_vector_type(2)));
typedef _Float16 f16x8 __attribute__((ext_vector_type(8)));
typedef float f32x4 __attribute__((ext_vector_type(4)));

__device__ inline float wred_sum(float v) {
#pragma unroll
  for (int d = 1; d < 64; d <<= 1) v += __shfl_xor(v, d, 64);
  return v;
}
__device__ inline float wred_max(float v) {
#pragma unroll
  for (int d = 1; d < 64; d <<= 1) v = fmaxf(v, __shfl_xor(v, d, 64));
  return v;
}
__device__ inline unsigned short f2h(float f) {
  return __builtin_bit_cast(unsigned short, (_Float16)f);
}
__device__ inline h2 bch2(unsigned int u) { return __builtin_bit_cast(h2, u); }
__device__ inline unsigned int h2u(h2 x) { return __builtin_bit_cast(unsigned int, x); }
__device__ inline f16x8 bcf16x8(uint4 u) { return __builtin_bit_cast(f16x8, u); }
__device__ inline h2 h2shfl_xor(h2 x, int d) {
  int xi = __builtin_bit_cast(int, x);
  xi = __shfl_xor(xi, d, 64);
  return __builtin_bit_cast(h2, xi);
}

// ---------------- CSR build ----------------
__global__ void k_hist(const int* __restrict__ dst, int* __restrict__ cnt, int E) {
  int e = blockIdx.x * 256 + threadIdx.x;
  if (e < E) atomicAdd(&cnt[dst[e]], 1);
}

// 3-phase multi-block scan (r7: single-block scan was 111 us on one CU)
__global__ __launch_bounds__(256) void k_scanA(const int* __restrict__ cnt,
                                               int* __restrict__ bsum, int n) {
  int tid = threadIdx.x;
  int base = blockIdx.x * 2048 + tid * 8;
  int s = 0;
#pragma unroll
  for (int i = 0; i < 8; ++i) {
    int idx = base + i;
    if (idx < n) s += cnt[idx];
  }
#pragma unroll
  for (int d = 1; d < 64; d <<= 1) s += __shfl_xor(s, d, 64);
  __shared__ int sm[4];
  int lane = tid & 63, wv = tid >> 6;
  if (lane == 0) sm[wv] = s;
  __syncthreads();
  if (tid == 0) bsum[blockIdx.x] = sm[0] + sm[1] + sm[2] + sm[3];
}

__global__ void k_scanB(const int* __restrict__ bsum, int* __restrict__ boff,
                        int* __restrict__ row, int nblk, int n) {
  if (threadIdx.x == 0 && blockIdx.x == 0) {
    int acc = 0;
    for (int i = 0; i < nblk; ++i) {
      boff[i] = acc;
      acc += bsum[i];
    }
    row[n] = acc;
  }
}

__global__ __launch_bounds__(256) void k_scanC(const int* __restrict__ cnt,
                                               const int* __restrict__ boff,
                                               int* __restrict__ row,
                                               int* __restrict__ cur, int n) {
  int tid = threadIdx.x;
  int lane = tid & 63, wv = tid >> 6;
  int base = blockIdx.x * 2048 + tid * 8;
  int v[8];
  int s = 0;
#pragma unroll
  for (int i = 0; i < 8; ++i) {
    int idx = base + i;
    v[i] = (idx < n) ? cnt[idx] : 0;
    s += v[i];
  }
  int incl = s;
#pragma unroll
  for (int d = 1; d < 64; d <<= 1) {
    int t = __shfl_up(incl, d, 64);
    if (lane >= d) incl += t;
  }
  __shared__ int wsum[4];
  if (lane == 63) wsum[wv] = incl;
  __syncthreads();
  int woff = 0;
  for (int i = 0; i < wv; ++i) woff += wsum[i];
  int excl = incl - s + woff + boff[blockIdx.x];
#pragma unroll
  for (int i = 0; i < 8; ++i) {
    int idx = base + i;
    if (idx < n) {
      row[idx] = excl;
      cur[idx] = excl;
      excl += v[i];
    }
  }
}

__global__ void k_scatter(const int* __restrict__ src, const int* __restrict__ dst,
                          int* __restrict__ cur, int* __restrict__ srcs, int E) {
  int e = blockIdx.x * 256 + threadIdx.x;
  if (e < E) {
    int d = dst[e];
    int pos = atomicAdd(&cur[d], 1);
    srcs[pos] = src[e];
  }
}

// ---------------- weight pre-pack: fp32 -> fp16 B-fragments ----------------
// Layout per layer (uint4 units): [0,1024) Bq (8ct x 2kk, x0.125), [1024,2048) Bk,
// [2048,3072) Bv, [3072,4096) Bout (4ct x 4kk), [4096,4608) B1, [4608,5120) B2.
// Frag elem i = W[(kk*32 + (lane>>4)*8 + i)*ld + ct*16 + (lane&15)] — same k-map as A loads.
__global__ __launch_bounds__(256) void k_wpack(
    const float* __restrict__ Wq, const float* __restrict__ Wk,
    const float* __restrict__ Wv, const float* __restrict__ Wout,
    const float* __restrict__ W1, const float* __restrict__ W2,
    uint4* __restrict__ P) {
  int t = blockIdx.x * 256 + threadIdx.x;  // 0..10239
  if (t >= 10240) return;
  int layer = t / 5120;
  int r = t - layer * 5120;
  const float* W;
  int idx, nkk, ld, base;
  float scale = 1.f;
  if (r < 1024) {
    W = Wq + layer * 64 * 128; idx = r; nkk = 2; ld = 128; scale = 0.125f; base = 0;
  } else if (r < 2048) {
    W = Wk + layer * 64 * 128; idx = r - 1024; nkk = 2; ld = 128; base = 1024;
  } else if (r < 3072) {
    W = Wv + layer * 64 * 128; idx = r - 2048; nkk = 2; ld = 128; base = 2048;
  } else if (r < 4096) {
    W = Wout + layer * 128 * 64; idx = r - 3072; nkk = 4; ld = 64; base = 3072;
  } else if (r < 4608) {
    W = W1 + layer * 64 * 64; idx = r - 4096; nkk = 2; ld = 64; base = 4096;
  } else {
    W = W2 + layer * 64 * 64; idx = r - 4608; nkk = 2; ld = 64; base = 4608;
  }
  int lane = idx & 63;
  int g = idx >> 6;
  int ct = g / nkk, kk = g - ct * nkk;
  int lc = lane & 15, lg = lane >> 4;
  unsigned short o[8];
#pragma unroll
  for (int i = 0; i < 8; ++i)
    o[i] = f2h(W[(kk * 32 + lg * 8 + i) * ld + ct * 16 + lc] * scale);
  P[layer * 5120 + base + idx] = *(const uint4*)o;
}

// ---------------- embedding: h = x @ emb_w + emb_b (32 nodes/block); writes h + hh ----
__global__ __launch_bounds__(256) void k_emb(const float* __restrict__ x,
                                             const float* __restrict__ w,
                                             const float* __restrict__ b,
                                             float* __restrict__ h,
                                             unsigned short* __restrict__ hh, int n) {
  __shared__ float xs[32][DIN];
  int tid = threadIdx.x;
  int nb = blockIdx.x * 32;
  for (int t = tid; t < 32 * DIN; t += 256) {
    int ni = t >> 7, k = t & 127;
    int gn = nb + ni;
    xs[ni][k] = (gn < n) ? x[(size_t)gn * DIN + k] : 0.f;
  }
  __syncthreads();
  int col = tid & 63, grp = tid >> 6;  // 4 groups x 8 nodes
  float acc[8];
#pragma unroll
  for (int u = 0; u < 8; ++u) acc[u] = b[col];
  for (int k = 0; k < DIN; k += 4) {
    float w0 = w[k * 64 + col], w1 = w[(k + 1) * 64 + col];
    float w2 = w[(k + 2) * 64 + col], w3 = w[(k + 3) * 64 + col];
#pragma unroll
    for (int u = 0; u < 8; ++u) {
      float4 xv = *(const float4*)&xs[grp * 8 + u][k];
      acc[u] += xv.x * w0 + xv.y * w1 + xv.z * w2 + xv.w * w3;
    }
  }
#pragma unroll
  for (int u = 0; u < 8; ++u) {
    int gn = nb + grp * 8 + u;
    if (gn < n) {
      h[(size_t)gn * 64 + col] = acc[u];
      hh[(size_t)gn * 64 + col] = f2h(acc[u]);
    }
  }
}

// ---------------- QKV (MFMA): one 16-node tile per wave ----------------
// Q = hh @ (Wq/8), K = hh @ Wk, V = hh @ Wv. Outputs fp16 into Qh[N,128], KVh[N,256].
__global__ __launch_bounds__(256) void k_qkv(
    const unsigned short* __restrict__ hh,
    const uint4* __restrict__ Bq, const uint4* __restrict__ Bk,
    const uint4* __restrict__ Bv,
    unsigned short* __restrict__ Qh, unsigned short* __restrict__ KVh, int n) {
  int lane = threadIdx.x & 63, wv = threadIdx.x >> 6;
  int nb = (blockIdx.x * 4 + wv) * 16;
  if (nb >= n) return;
  int lc = lane & 15, lg = lane >> 4;

  const uint4* ap = (const uint4*)(hh + (size_t)(nb + lc) * 64);
  f16x8 af0 = bcf16x8(ap[lg]);      // k = lg*8..+7
  f16x8 af1 = bcf16x8(ap[4 + lg]);  // k = 32+lg*8..+7

  // Q
  {
    f32x4 acc[8] = {};
#pragma unroll
    for (int ct = 0; ct < 8; ++ct) {
      acc[ct] = __builtin_amdgcn_mfma_f32_16x16x32_f16(
          af0, bcf16x8(Bq[(ct * 2 + 0) * 64 + lane]), acc[ct], 0, 0, 0);
      acc[ct] = __builtin_amdgcn_mfma_f32_16x16x32_f16(
          af1, bcf16x8(Bq[(ct * 2 + 1) * 64 + lane]), acc[ct], 0, 0, 0);
    }
#pragma unroll
    for (int ct = 0; ct < 8; ++ct)
#pragma unroll
      for (int r = 0; r < 4; ++r) {
        int gn = nb + lg * 4 + r;
        if (gn < n) Qh[(size_t)gn * 128 + ct * 16 + lc] = f2h(acc[ct][r]);
      }
  }
  // K
  {
    f32x4 acc[8] = {};
#pragma unroll
    for (int ct = 0; ct < 8; ++ct) {
      acc[ct] = __builtin_amdgcn_mfma_f32_16x16x32_f16(
          af0, bcf16x8(Bk[(ct * 2 + 0) * 64 + lane]), acc[ct], 0, 0, 0);
      acc[ct] = __builtin_amdgcn_mfma_f32_16x16x32_f16(
          af1, bcf16x8(Bk[(ct * 2 + 1) * 64 + lane]), acc[ct], 0, 0, 0);
    }
#pragma unroll
    for (int ct = 0; ct < 8; ++ct)
#pragma unroll
      for (int r = 0; r < 4; ++r) {
        int gn = nb + lg * 4 + r;
        if (gn < n) KVh[(size_t)gn * 256 + ct * 16 + lc] = f2h(acc[ct][r]);
      }
  }
  // V
  {
    f32x4 acc[8] = {};
#pragma unroll
    for (int ct = 0; ct < 8; ++ct) {
      acc[ct] = __builtin_amdgcn_mfma_f32_16x16x32_f16(
          af0, bcf16x8(Bv[(ct * 2 + 0) * 64 + lane]), acc[ct], 0, 0, 0);
      acc[ct] = __builtin_amdgcn_mfma_f32_16x16x32_f16(
          af1, bcf16x8(Bv[(ct * 2 + 1) * 64 + lane]), acc[ct], 0, 0, 0);
    }
#pragma unroll
    for (int ct = 0; ct < 8; ++ct)
#pragma unroll
      for (int r = 0; r < 4; ++r) {
        int gn = nb + lg * 4 + r;
        if (gn < n) KVh[(size_t)gn * 256 + 128 + ct * 16 + lc] = f2h(acc[ct][r]);
      }
  }
}

// ---------------- attention gather+softmax: aggrh[N,128] fp16 normalized ----------------
__global__ __launch_bounds__(256) void k_attn(
    const unsigned short* __restrict__ Qh, const unsigned short* __restrict__ KVh,
    const int* __restrict__ row, const int* __restrict__ srcs,
    unsigned short* __restrict__ aggrh, int n) {
  int lane = threadIdx.x & 63;
  int w = threadIdx.x >> 6;
  int node = blockIdx.x * 4 + w;
  if (node >= n) return;  // no barriers in this kernel
  int sl = lane & 15, gi = lane >> 4;

  uint4 qr = *(const uint4*)(Qh + (size_t)node * 128 + sl * 8);
  h2 q0 = bch2(qr.x), q1 = bch2(qr.y), q2 = bch2(qr.z), q3 = bch2(qr.w);

  int rs = row[node], re = row[node + 1];
  int deg = re - rs;
  float den = 0.f;
  h2 acc0 = {0, 0}, acc1 = {0, 0}, acc2 = {0, 0}, acc3 = {0, 0};

  if (deg > 0) {
    int iters = (deg + 3) >> 2;
    uint4 Kb[4], Vb[4];
    int sxb[4];
#pragma unroll
    for (int s = 0; s < 4; ++s) {
      if (s < iters) {
        int ei = rs + s * 4 + gi;
        int sx = (ei < re) ? srcs[ei] : srcs[rs];
        const unsigned short* kv = KVh + (size_t)sx * 256 + sl * 8;
        Kb[s] = *(const uint4*)kv;
        Vb[s] = *(const uint4*)(kv + 128);
      }
      int ei2 = rs + (s + 4) * 4 + gi;
      sxb[s] = (ei2 < re) ? srcs[ei2] : srcs[rs];
    }
    for (int it = 0; it < iters; it += 4) {
#pragma unroll
      for (int s = 0; s < 4; ++s) {
        int cit = it + s;
        if (cit < iters) {  // wave-uniform
          uint4 Kc = Kb[s], Vc = Vb[s];
          if (cit + 4 < iters) {
            const unsigned short* kv = KVh + (size_t)sxb[s] * 256 + sl * 8;
            Kb[s] = *(const uint4*)kv;
            Vb[s] = *(const uint4*)(kv + 128);
          }
          {
            int ei3 = rs + (cit + 8) * 4 + gi;
            sxb[s] = (ei3 < re) ? srcs[ei3] : srcs[rs];
          }
          float sc = __builtin_amdgcn_fdot2(bch2(Kc.x), q0, 0.f, false);
          sc = __builtin_amdgcn_fdot2(bch2(Kc.y), q1, sc, false);
          sc = __builtin_amdgcn_fdot2(bch2(Kc.z), q2, sc, false);
          sc = __builtin_amdgcn_fdot2(bch2(Kc.w), q3, sc, false);
          sc += __shfl_xor(sc, 1, 64);
          sc += __shfl_xor(sc, 2, 64);
          sc += __shfl_xor(sc, 4, 64);
          bool ev = (rs + cit * 4 + gi) < re;
          float wgt = ev ? __expf(sc) : 0.f;
          den += wgt;
          _Float16 wh = (_Float16)wgt;
          h2 W = {wh, wh};
          acc0 += W * bch2(Vc.x);
          acc1 += W * bch2(Vc.y);
          acc2 += W * bch2(Vc.z);
          acc3 += W * bch2(Vc.w);
        }
      }
    }
  }
#pragma unroll
  for (int d = 16; d < 64; d <<= 1) {
    den += __shfl_xor(den, d, 64);
    acc0 += h2shfl_xor(acc0, d);
    acc1 += h2shfl_xor(acc1, d);
    acc2 += h2shfl_xor(acc2, d);
    acc3 += h2shfl_xor(acc3, d);
  }
  float inv = fminf(1.f / (den + 1e-16f), 60000.f);
  if (lane < 16) {
    _Float16 ih = (_Float16)inv;
    h2 I = {ih, ih};
    uint4 o;
    o.x = h2u(acc0 * I);
    o.y = h2u(acc1 * I);
    o.z = h2u(acc2 * I);
    o.w = h2u(acc3 * I);
    *(uint4*)(aggrh + (size_t)node * 128 + sl * 8) = o;
  }
}

// ---------------- post (MFMA): Wout -> +res -> LN -> FFN. One 16-node tile per wave ----
// C/D layout (HW-verified): col = lane&15, row = (lane>>4)*4 + reg.
__global__ __launch_bounds__(256) void k_post(
    const unsigned short* __restrict__ aggrh, float* __restrict__ h,
    unsigned short* __restrict__ hh,
    const uint4* __restrict__ Bout, const float* __restrict__ bout,
    const float* __restrict__ lng, const float* __restrict__ lnb,
    const uint4* __restrict__ B1, const float* __restrict__ b1,
    const uint4* __restrict__ B2, const float* __restrict__ b2, int n) {
  __shared__ unsigned short red[4][16 * 88];  // per-wave A-redistribution buffer (fp16)
  int lane = threadIdx.x & 63, wv = threadIdx.x >> 6;
  int nb = (blockIdx.x * 4 + wv) * 16;
  if (nb >= n) return;  // no barriers in this kernel
  int lc = lane & 15, lg = lane >> 4;

  // GEMM1: O[16,64] = aggr[16,128] @ Wout
  f32x4 acc[4] = {{0, 0, 0, 0}, {0, 0, 0, 0}, {0, 0, 0, 0}, {0, 0, 0, 0}};
  const uint4* arow_p = (const uint4*)(aggrh + (size_t)(nb + lc) * 128);
#pragma unroll
  for (int kk = 0; kk < 4; ++kk) {
    f16x8 af = bcf16x8(arow_p[kk * 4 + lg]);
#pragma unroll
    for (int ct = 0; ct < 4; ++ct)
      acc[ct] = __builtin_amdgcn_mfma_f32_16x16x32_f16(
          af, bcf16x8(Bout[(ct * 4 + kk) * 64 + lane]), acc[ct], 0, 0, 0);
  }

  // bias + residual + layernorm (rows r = lg*4+0..3, cols ct*16+lc)
  float x[4][4], hl[4][4];  // [r][ct]
#pragma unroll
  for (int ct = 0; ct < 4; ++ct) {
    float bo = bout[ct * 16 + lc];
#pragma unroll
    for (int r = 0; r < 4; ++r)
      x[r][ct] = acc[ct][r] + bo + h[(size_t)(nb + lg * 4 + r) * 64 + ct * 16 + lc];
  }
  float g[4], bb[4];
#pragma unroll
  for (int ct = 0; ct < 4; ++ct) {
    g[ct] = lng[ct * 16 + lc];
    bb[ct] = lnb[ct * 16 + lc];
  }
#pragma unroll
  for (int r = 0; r < 4; ++r) {
    float s = x[r][0] + x[r][1] + x[r][2] + x[r][3];
    s += __shfl_xor(s, 1, 64);
    s += __shfl_xor(s, 2, 64);
    s += __shfl_xor(s, 4, 64);
    s += __shfl_xor(s, 8, 64);
    float mu = s * (1.f / 64.f);
    float s2 = 0.f;
#pragma unroll
    for (int ct = 0; ct < 4; ++ct) {
      float xc = x[r][ct] - mu;
      s2 += xc * xc;
    }
    s2 += __shfl_xor(s2, 1, 64);
    s2 += __shfl_xor(s2, 2, 64);
    s2 += __shfl_xor(s2, 4, 64);
    s2 += __shfl_xor(s2, 8, 64);
    float inv = rsqrtf(s2 * (1.f / 64.f) + 1e-5f);
#pragma unroll
    for (int ct = 0; ct < 4; ++ct) {
      hl[r][ct] = (x[r][ct] - mu) * inv * g[ct] + bb[ct];
      red[wv][(lg * 4 + r) * 88 + ct * 16 + lc] = f2h(hl[r][ct]);
    }
  }

  // GEMM2: T = relu(hl @ W1 + b1)
  f32x4 acc2[4] = {{0, 0, 0, 0}, {0, 0, 0, 0}, {0, 0, 0, 0}, {0, 0, 0, 0}};
#pragma unroll
  for (int kk = 0; kk < 2; ++kk) {
    f16x8 af = bcf16x8(*(const uint4*)&red[wv][lc * 88 + kk * 32 + lg * 8]);
#pragma unroll
    for (int ct = 0; ct < 4; ++ct)
      acc2[ct] = __builtin_amdgcn_mfma_f32_16x16x32_f16(
          af, bcf16x8(B1[(ct * 2 + kk) * 64 + lane]), acc2[ct], 0, 0, 0);
  }
#pragma unroll
  for (int ct = 0; ct < 4; ++ct) {
    float b1c = b1[ct * 16 + lc];
#pragma unroll
    for (int r = 0; r < 4; ++r)
      red[wv][(lg * 4 + r) * 88 + ct * 16 + lc] = f2h(fmaxf(acc2[ct][r] + b1c, 0.f));
  }

  // GEMM3: out = hl + T @ W2 + b2
  f32x4 acc3[4] = {{0, 0, 0, 0}, {0, 0, 0, 0}, {0, 0, 0, 0}, {0, 0, 0, 0}};
#pragma unroll
  for (int kk = 0; kk < 2; ++kk) {
    f16x8 af = bcf16x8(*(const uint4*)&red[wv][lc * 88 + kk * 32 + lg * 8]);
#pragma unroll
    for (int ct = 0; ct < 4; ++ct)
      acc3[ct] = __builtin_amdgcn_mfma_f32_16x16x32_f16(
          af, bcf16x8(B2[(ct * 2 + kk) * 64 + lane]), acc3[ct], 0, 0, 0);
  }
#pragma unroll
  for (int ct = 0; ct < 4; ++ct) {
    float b2c = b2[ct * 16 + lc];
#pragma unroll
    for (int r = 0; r < 4; ++r) {
      int gn = nb + lg * 4 + r;
      if (gn < n) {
        float v = hl[r][ct] + acc3[ct][r] + b2c;
        h[(size_t)gn * 64 + ct * 16 + lc] = v;
        hh[(size_t)gn * 64 + ct * 16 + lc] = f2h(v);
      }
    }
  }
}

// ---------------- output: log_softmax(h @ out_w + out_b) (16 nodes/block) ----------------
__global__ __launch_bounds__(256) void k_out(const float* __restrict__ h,
                                             const float* __restrict__ w,
                                             const float* __restrict__ b,
                                             float* __restrict__ out, int n) {
  __shared__ float s_h[16][64];
  int tid = threadIdx.x;
  int nb = blockIdx.x * 16;
  for (int t = tid; t < 16 * 64; t += 256) {
    int ni = t >> 6;
    int gn = nb + ni;
    s_h[ni][t & 63] = (gn < n) ? h[(size_t)gn * 64 + (t & 63)] : 0.f;
  }
  __syncthreads();
  int lane = tid & 63, wv = tid >> 6;
  for (int u = 0; u < 4; ++u) {
    int li = wv * 4 + u;
    int node = nb + li;
    float lv = -3.0e38f;
    if (lane < 40) {
      lv = b[lane];
#pragma unroll 8
      for (int j = 0; j < 64; ++j) lv += s_h[li][j] * w[j * 40 + lane];
    }
    float m = wred_max(lv);
    float ex = (lane < 40) ? __expf(lv - m) : 0.f;
    float s = wred_sum(ex);
    if (node < n && lane < 40) out[(size_t)node * 40 + lane] = lv - m - logf(s);
  }
}

extern "C" void kernel_launch(void* const* d_in, const int* in_sizes, int n_in,
                              void* d_out, int out_size, void* d_ws, size_t ws_size,
                              hipStream_t stream) {
  const float* x     = (const float*)d_in[0];
  const int*   ei    = (const int*)d_in[1];
  const float* emb_w = (const float*)d_in[2];
  const float* emb_b = (const float*)d_in[3];
  const float* Wq    = (const float*)d_in[4];   // [2,64,128]
  const float* Wk    = (const float*)d_in[5];
  const float* Wv    = (const float*)d_in[6];
  const float* Wout  = (const float*)d_in[7];   // [2,128,64]
  const float* bout  = (const float*)d_in[8];
  const float* ln_g  = (const float*)d_in[9];
  const float* ln_b  = (const float*)d_in[10];
  const float* W1    = (const float*)d_in[11];  // [2,64,64]
  const float* b1    = (const float*)d_in[12];
  const float* W2    = (const float*)d_in[13];
  const float* b2    = (const float*)d_in[14];
  const float* out_w = (const float*)d_in[15];  // [64,40]
  const float* out_b = (const float*)d_in[16];
  float* out = (float*)d_out;

  const int n = in_sizes[0] / DIN;  // 50000
  const int E = in_sizes[1] / 2;    // 800000

  char* ws = (char*)d_ws;
  size_t off = 0;
  auto alloc = [&](size_t bytes) {
    void* p = ws + off;
    off = (off + bytes + 255) & ~(size_t)255;
    return p;
  };
  float* h              = (float*)alloc((size_t)n * 64 * 4);
  unsigned short* hh    = (unsigned short*)alloc((size_t)n * 64 * 2);
  unsigned short* Qh    = (unsigned short*)alloc((size_t)n * 128 * 2);
  unsigned short* KVh   = (unsigned short*)alloc((size_t)n * 256 * 2);
  unsigned short* aggrh = (unsigned short*)alloc((size_t)n * 128 * 2);
  int* cnt              = (int*)alloc((size_t)n * 4);
  int* rowp             = (int*)alloc((size_t)(n + 1) * 4);
  int* cur              = (int*)alloc((size_t)n * 4);
  int* srcs             = (int*)alloc((size_t)E * 4);
  uint4* WP             = (uint4*)alloc((size_t)2 * 5120 * 16);
  int nScanBlk          = (n + 2047) / 2048;
  int* bsum             = (int*)alloc((size_t)nScanBlk * 4);
  int* boff             = (int*)alloc((size_t)nScanBlk * 4);

  const int* src = ei;
  const int* dst = ei + E;

  hipMemsetAsync(cnt, 0, (size_t)n * 4, stream);
  k_hist<<<(E + 255) / 256, 256, 0, stream>>>(dst, cnt, E);
  k_scanA<<<nScanBlk, 256, 0, stream>>>(cnt, bsum, n);
  k_scanB<<<1, 64, 0, stream>>>(bsum, boff, rowp, nScanBlk, n);
  k_scanC<<<nScanBlk, 256, 0, stream>>>(cnt, boff, rowp, cur, n);
  k_scatter<<<(E + 255) / 256, 256, 0, stream>>>(src, dst, cur, srcs, E);

  k_wpack<<<40, 256, 0, stream>>>(Wq, Wk, Wv, Wout, W1, W2, WP);
  k_emb<<<(n + 31) / 32, 256, 0, stream>>>(x, emb_w, emb_b, h, hh, n);

  for (int l = 0; l < 2; ++l) {
    const uint4* L = WP + (size_t)l * 5120;
    k_qkv<<<(n + 63) / 64, 256, 0, stream>>>(hh, L, L + 1024, L + 2048, Qh, KVh, n);
    k_attn<<<(n + 3) / 4, 256, 0, stream>>>(Qh, KVh, rowp, srcs, aggrh, n);
    k_post<<<(n + 63) / 64, 256, 0, stream>>>(
        aggrh, h, hh, L + 3072, bout + (size_t)l * 64,
        ln_g + (size_t)l * 64, ln_b + (size_t)l * 64, L + 4096,
        b1 + (size_t)l * 64, L + 4608, b2 + (size_t)l * 64, n);
  }

  k_out<<<(n + 15) / 16, 256, 0, stream>>>(h, out_w, out_b, out, n);
}